// Round 1
// baseline (804.496 us; speedup 1.0000x reference)
//
#include <hip/hip_runtime.h>
#include <hip/hip_bf16.h>
#include <math.h>

// Problem dims (compile-time)
#define L     2048
#define DM    1024
#define DI    2048
#define DCONV 4
#define RNK   16
#define NST   16
#define CCH   32          // number of scan chunks
#define TCH   (L / CCH)   // steps per chunk = 64

// ---------------- GEMM: C[M,N] = A[M,K] * B[N,K]^T  (both row-major, dot of rows)
#define BM 128
#define BN 128
#define BK 8

__global__ __launch_bounds__(256) void gemm_nt(const float* __restrict__ A,
                                               const float* __restrict__ B,
                                               float* __restrict__ C,
                                               int M, int N, int K) {
    __shared__ float As[BK][BM];
    __shared__ float Bs[BK][BN];
    const int tid = threadIdx.x;
    const int bm = blockIdx.x * BM;
    const int bn = blockIdx.y * BN;
    const int tx = tid & 15, ty = tid >> 4;

    float acc[8][8];
#pragma unroll
    for (int i = 0; i < 8; ++i)
#pragma unroll
        for (int j = 0; j < 8; ++j) acc[i][j] = 0.f;

    const int lr = tid >> 1;        // 0..127 (row within tile)
    const int lk = (tid & 1) * 4;   // 0 or 4

    for (int k0 = 0; k0 < K; k0 += BK) {
        float4 av = *(const float4*)(A + (size_t)(bm + lr) * K + k0 + lk);
        float4 bv = *(const float4*)(B + (size_t)(bn + lr) * K + k0 + lk);
        As[lk + 0][lr] = av.x; As[lk + 1][lr] = av.y;
        As[lk + 2][lr] = av.z; As[lk + 3][lr] = av.w;
        Bs[lk + 0][lr] = bv.x; Bs[lk + 1][lr] = bv.y;
        Bs[lk + 2][lr] = bv.z; Bs[lk + 3][lr] = bv.w;
        __syncthreads();
#pragma unroll
        for (int kk = 0; kk < BK; ++kk) {
            float a[8], b[8];
#pragma unroll
            for (int i = 0; i < 8; ++i) a[i] = As[kk][ty * 8 + i];
#pragma unroll
            for (int j = 0; j < 8; ++j) b[j] = Bs[kk][tx * 8 + j];
#pragma unroll
            for (int i = 0; i < 8; ++i)
#pragma unroll
                for (int j = 0; j < 8; ++j) acc[i][j] += a[i] * b[j];
        }
        __syncthreads();
    }

#pragma unroll
    for (int i = 0; i < 8; ++i) {
        float* crow = C + (size_t)(bm + ty * 8 + i) * N + bn + tx * 8;
#pragma unroll
        for (int j = 0; j < 8; ++j) crow[j] = acc[i][j];
    }
}

// ---------------- depthwise causal conv (k=4) + silu
__global__ __launch_bounds__(256) void conv_silu_kernel(const float* __restrict__ xz,
                                                        const float* __restrict__ cw,
                                                        const float* __restrict__ cb,
                                                        float* __restrict__ xc) {
    int idx = blockIdx.x * 256 + threadIdx.x;   // l*DI + d
    int l = idx >> 11;
    int d = idx & (DI - 1);
    float s = cb[d];
#pragma unroll
    for (int k = 0; k < DCONV; ++k) {
        int t = l - (DCONV - 1) + k;
        if (t >= 0) s += cw[d * DCONV + k] * xz[(size_t)t * (2 * DI) + d];
    }
    xc[idx] = s / (1.f + expf(-s));   // silu
}

// ---------------- x_dbl[l, 0..47] = xc[l,:] @ W_x[j,:]
__global__ __launch_bounds__(256) void xdbl_kernel(const float* __restrict__ xc,
                                                   const float* __restrict__ Wx,
                                                   float* __restrict__ xdbl) {
    __shared__ float row[DI];
    const int l = blockIdx.x;
    for (int i = threadIdx.x; i < DI / 4; i += 256)
        *(float4*)(row + i * 4) = *(const float4*)(xc + (size_t)l * DI + i * 4);
    __syncthreads();
    const int wave = threadIdx.x >> 6;
    const int lane = threadIdx.x & 63;
    for (int j = wave; j < RNK + 2 * NST; j += 4) {
        float s = 0.f;
        for (int k = lane; k < DI; k += 64) s += row[k] * Wx[(size_t)j * DI + k];
#pragma unroll
        for (int off = 32; off; off >>= 1) s += __shfl_down(s, off);
        if (lane == 0) xdbl[l * 48 + j] = s;
    }
}

// ---------------- delta[l,d] = softplus(xdbl[l,:16] @ W_dt[d,:] + b_dt[d])
__global__ __launch_bounds__(256) void delta_kernel(const float* __restrict__ xdbl,
                                                    const float* __restrict__ Wdt,
                                                    const float* __restrict__ bdt,
                                                    float* __restrict__ delta) {
    int idx = blockIdx.x * 256 + threadIdx.x;
    int l = idx >> 11;
    int d = idx & (DI - 1);
    float s = bdt[d];
#pragma unroll
    for (int r = 0; r < RNK; ++r) s += xdbl[l * 48 + r] * Wdt[d * RNK + r];
    delta[idx] = fmaxf(s, 0.f) + log1pf(expf(-fabsf(s)));   // jax softplus
}

// ---------------- scan phase A: per-chunk local scan + carry multiplier
__global__ __launch_bounds__(256) void scan_a(const float* __restrict__ delta,
                                              const float* __restrict__ xc,
                                              const float* __restrict__ xdbl,
                                              const float* __restrict__ A_log,
                                              float* __restrict__ hloc,
                                              float* __restrict__ aexp) {
    int idx = blockIdx.x * 256 + threadIdx.x;  // c*DI*NST + d*NST + n
    int n = idx & (NST - 1);
    int d = (idx >> 4) & (DI - 1);
    int c = idx >> 15;
    float Adn = -expf(A_log[d * NST + n]);
    float h = 0.f, dsum = 0.f;
    int t0 = c * TCH;
    for (int t = t0; t < t0 + TCH; ++t) {
        float dl = delta[(size_t)t * DI + d];
        float u  = xc[(size_t)t * DI + d];
        float b  = xdbl[t * 48 + RNK + n];
        dsum += dl;
        h = expf(Adn * dl) * h + dl * b * u;
    }
    hloc[idx] = h;
    aexp[idx] = expf(Adn * dsum);
}

// ---------------- scan phase B: sequential combine over chunks
__global__ __launch_bounds__(256) void scan_b(const float* __restrict__ hloc,
                                              const float* __restrict__ aexp,
                                              float* __restrict__ hinit) {
    int idx = blockIdx.x * 256 + threadIdx.x;   // d*NST+n, DI*NST threads
    float h = 0.f;
    for (int c = 0; c < CCH; ++c) {
        hinit[c * (DI * NST) + idx] = h;
        h = aexp[c * (DI * NST) + idx] * h + hloc[c * (DI * NST) + idx];
    }
}

// ---------------- scan phase C: replay with correct init, reduce over n, write y
__global__ __launch_bounds__(256) void scan_c(const float* __restrict__ delta,
                                              const float* __restrict__ xc,
                                              const float* __restrict__ xdbl,
                                              const float* __restrict__ A_log,
                                              const float* __restrict__ hinit,
                                              float* __restrict__ y /* stride 2*DI */) {
    int idx = blockIdx.x * 256 + threadIdx.x;  // c*DI*NST + d*NST + n
    int n = idx & (NST - 1);
    int d = (idx >> 4) & (DI - 1);
    int c = idx >> 15;
    float Adn = -expf(A_log[d * NST + n]);
    float h = hinit[idx];
    int t0 = c * TCH;
    for (int t = t0; t < t0 + TCH; ++t) {
        float dl = delta[(size_t)t * DI + d];
        float u  = xc[(size_t)t * DI + d];
        float b  = xdbl[t * 48 + RNK + n];
        float ct = xdbl[t * 48 + RNK + NST + n];
        h = expf(Adn * dl) * h + dl * b * u;
        float p = h * ct;
        p += __shfl_xor(p, 1);
        p += __shfl_xor(p, 2);
        p += __shfl_xor(p, 4);
        p += __shfl_xor(p, 8);
        if (n == 0) y[(size_t)t * (2 * DI) + d] = p;
    }
}

// ---------------- gate: g = (y + xc*D) * silu(res)
__global__ __launch_bounds__(256) void gate_kernel(const float* __restrict__ xz, // y in [:, :DI], res in [:, DI:]
                                                   const float* __restrict__ xc,
                                                   const float* __restrict__ Dp,
                                                   float* __restrict__ g) {
    int idx = blockIdx.x * 256 + threadIdx.x;
    int l = idx >> 11;
    int d = idx & (DI - 1);
    float yv = xz[(size_t)l * (2 * DI) + d];
    float rv = xz[(size_t)l * (2 * DI) + DI + d];
    g[idx] = (yv + xc[idx] * Dp[d]) * (rv / (1.f + expf(-rv)));
}

extern "C" void kernel_launch(void* const* d_in, const int* in_sizes, int n_in,
                              void* d_out, int out_size, void* d_ws, size_t ws_size,
                              hipStream_t stream) {
    const float* x      = (const float*)d_in[0];
    const float* W_in   = (const float*)d_in[1];
    const float* conv_w = (const float*)d_in[2];
    const float* conv_b = (const float*)d_in[3];
    const float* W_x    = (const float*)d_in[4];
    const float* W_dt   = (const float*)d_in[5];
    const float* b_dt   = (const float*)d_in[6];
    const float* A_log  = (const float*)d_in[7];
    const float* Dp     = (const float*)d_in[8];
    const float* W_out  = (const float*)d_in[9];
    float* out = (float*)d_out;

    float* ws = (float*)d_ws;
    // workspace layout (floats)
    const size_t XZ_OFF    = 0;                       // L*2*DI = 8388608
    const size_t XC_OFF    = XZ_OFF + (size_t)L * 2 * DI;      // 4194304
    const size_t DELTA_OFF = XC_OFF + (size_t)L * DI;          // 4194304
    const size_t XDBL_OFF  = DELTA_OFF + (size_t)L * DI;       // 98304 (pad 131072)
    const size_t HLOC_OFF  = XDBL_OFF + 131072;                // CCH*DI*NST = 1048576
    const size_t AEXP_OFF  = HLOC_OFF + (size_t)CCH * DI * NST;
    const size_t HINIT_OFF = AEXP_OFF + (size_t)CCH * DI * NST;

    float* xz    = ws + XZ_OFF;
    float* xc    = ws + XC_OFF;
    float* delta = ws + DELTA_OFF;
    float* xdbl  = ws + XDBL_OFF;
    float* hloc  = ws + HLOC_OFF;
    float* aexp  = ws + AEXP_OFF;
    float* hinit = ws + HINIT_OFF;
    float* g     = delta;   // reuse delta buffer after scan
    float* y     = xz;      // y written into xz[:, :DI] (raw conv input is dead)

    // 1. in_proj: xz[L, 2*DI] = x[L,DM] @ W_in[2*DI,DM]^T
    {
        dim3 grid(L / BM, (2 * DI) / BN);
        gemm_nt<<<grid, 256, 0, stream>>>(x, W_in, xz, L, 2 * DI, DM);
    }
    // 2. conv + silu -> xc
    conv_silu_kernel<<<(L * DI) / 256, 256, 0, stream>>>(xz, conv_w, conv_b, xc);
    // 3. x_dbl
    xdbl_kernel<<<L, 256, 0, stream>>>(xc, W_x, xdbl);
    // 4. delta
    delta_kernel<<<(L * DI) / 256, 256, 0, stream>>>(xdbl, W_dt, b_dt, delta);
    // 5. scan phase A
    scan_a<<<(CCH * DI * NST) / 256, 256, 0, stream>>>(delta, xc, xdbl, A_log, hloc, aexp);
    // 6. scan phase B
    scan_b<<<(DI * NST) / 256, 256, 0, stream>>>(hloc, aexp, hinit);
    // 7. scan phase C -> y (into xz first half)
    scan_c<<<(CCH * DI * NST) / 256, 256, 0, stream>>>(delta, xc, xdbl, A_log, hinit, y);
    // 8. gate -> g (reuses delta buffer)
    gate_kernel<<<(L * DI) / 256, 256, 0, stream>>>(xz, xc, Dp, g);
    // 9. out_proj: out[L,DM] = g[L,DI] @ W_out[DM,DI]^T
    {
        dim3 grid(L / BM, DM / BN);
        gemm_nt<<<grid, 256, 0, stream>>>(g, W_out, out, L, DM, DI);
    }
}

// Round 2
// 452.424 us; speedup vs baseline: 1.7782x; 1.7782x over previous
//
#include <hip/hip_runtime.h>
#include <hip/hip_bf16.h>
#include <math.h>

// Problem dims (compile-time)
#define L     2048
#define DM    1024
#define DI    2048
#define DCONV 4
#define RNK   16
#define NST   16
#define CCH   32          // number of scan chunks
#define TCH   (L / CCH)   // steps per chunk = 64

typedef __attribute__((ext_vector_type(8))) short bf16x8;   // 8 bf16 in 4 VGPRs
typedef __attribute__((ext_vector_type(4))) float f32x4;
typedef __attribute__((ext_vector_type(4))) unsigned short u16x4;

// ---- fp32 -> bf16 (RNE) split helpers ----
__device__ __forceinline__ unsigned short bfh(float f) {
    unsigned u = __float_as_uint(f);
    unsigned r = u + 0x7FFFu + ((u >> 16) & 1u);
    return (unsigned short)(r >> 16);
}
__device__ __forceinline__ float bf2f(unsigned short h) {
    return __uint_as_float(((unsigned)h) << 16);
}

// Swizzled LDS byte offset for a [R][32]-bf16 tile (row = 64 B).
// 16B chunk q (k/8) is XORed with (row>>1)&3 so that the fragment read
// (16 lanes, consecutive rows, same q) spreads over 8 distinct 16B slots
// per 128B bank cycle -> <=2-way conflict (free per m136).
__device__ __forceinline__ int swz_byte(int row, int q) {
    return row * 64 + ((q ^ ((row >> 1) & 3)) << 4);
}

// Stage an R x 32 fp32 tile into hi/lo bf16 LDS tiles (swizzled).
template<int R>
__device__ __forceinline__ void stage_tile(const float* __restrict__ src, int K, int k0,
                                           unsigned short* sh, unsigned short* sl, int tid) {
#pragma unroll
    for (int c0 = 0; c0 < R * 8; c0 += 256) {
        int c = c0 + tid;
        int row = c >> 3, cc = c & 7;              // cc: which float4 of the row
        float4 v = *(const float4*)(src + (size_t)row * K + k0 + cc * 4);
        unsigned short hx = bfh(v.x), hy = bfh(v.y), hz = bfh(v.z), hw = bfh(v.w);
        unsigned short lx = bfh(v.x - bf2f(hx));
        unsigned short ly = bfh(v.y - bf2f(hy));
        unsigned short lz = bfh(v.z - bf2f(hz));
        unsigned short lw = bfh(v.w - bf2f(hw));
        int byte = swz_byte(row, cc >> 1) + ((cc & 1) << 3);   // 8B half of the 16B chunk
        u16x4 hv = {hx, hy, hz, hw};
        u16x4 lv = {lx, ly, lz, lw};
        *(u16x4*)((char*)sh + byte) = hv;
        *(u16x4*)((char*)sl + byte) = lv;
    }
}

__device__ __forceinline__ bf16x8 rdfrag(const unsigned short* base, int row, int q) {
    return *(const bf16x8*)((const char*)base + swz_byte(row, q));
}

// C[M,N] = A[M,K] * B[N,K]^T in fp32-via-3xbf16-MFMA.
// 4 waves in 2x2 arrangement; wave tile (BM/2)x(BN/2); 16x16x32 MFMA.
template<int BM, int BN>
__global__ __launch_bounds__(256) void gemm_bt3(const float* __restrict__ A,
                                                const float* __restrict__ B,
                                                float* __restrict__ C,
                                                int M, int N, int K) {
    __shared__ __align__(16) unsigned short Ah[BM * 32];
    __shared__ __align__(16) unsigned short Al[BM * 32];
    __shared__ __align__(16) unsigned short Bh[BN * 32];
    __shared__ __align__(16) unsigned short Bl[BN * 32];

    const int tid = threadIdx.x;
    const int bm = blockIdx.x * BM, bn = blockIdx.y * BN;
    const int l = tid & 63, wv = tid >> 6;
    const int wr = (wv >> 1) * (BM / 2), wc = (wv & 1) * (BN / 2);
    constexpr int MR = BM / 32, NR = BN / 32;
    const int fr = l & 15, q = l >> 4;

    f32x4 acc[MR][NR];
#pragma unroll
    for (int m = 0; m < MR; ++m)
#pragma unroll
        for (int n = 0; n < NR; ++n) acc[m][n] = (f32x4){0.f, 0.f, 0.f, 0.f};

    const float* Ab = A + (size_t)bm * K;
    const float* Bb = B + (size_t)bn * K;

    for (int k0 = 0; k0 < K; k0 += 32) {
        stage_tile<BM>(Ab, K, k0, Ah, Al, tid);
        stage_tile<BN>(Bb, K, k0, Bh, Bl, tid);
        __syncthreads();

        bf16x8 ah[MR], av[MR], bh[NR], bv[NR];
#pragma unroll
        for (int m = 0; m < MR; ++m) {
            int row = wr + m * 16 + fr;
            ah[m] = rdfrag(Ah, row, q);
            av[m] = rdfrag(Al, row, q);
        }
#pragma unroll
        for (int n = 0; n < NR; ++n) {
            int row = wc + n * 16 + fr;
            bh[n] = rdfrag(Bh, row, q);
            bv[n] = rdfrag(Bl, row, q);
        }
#pragma unroll
        for (int m = 0; m < MR; ++m)
#pragma unroll
            for (int n = 0; n < NR; ++n) {
                acc[m][n] = __builtin_amdgcn_mfma_f32_16x16x32_bf16(av[m], bh[n], acc[m][n], 0, 0, 0);
                acc[m][n] = __builtin_amdgcn_mfma_f32_16x16x32_bf16(ah[m], bv[n], acc[m][n], 0, 0, 0);
                acc[m][n] = __builtin_amdgcn_mfma_f32_16x16x32_bf16(ah[m], bh[n], acc[m][n], 0, 0, 0);
            }
        __syncthreads();
    }

    // C/D layout: col = lane&15, row = (lane>>4)*4 + reg  [m89/m91]
#pragma unroll
    for (int m = 0; m < MR; ++m)
#pragma unroll
        for (int n = 0; n < NR; ++n) {
            int row0 = bm + wr + m * 16 + q * 4;
            int col  = bn + wc + n * 16 + fr;
#pragma unroll
            for (int r = 0; r < 4; ++r)
                C[(size_t)(row0 + r) * N + col] = acc[m][n][r];
        }
}

// ---------------- depthwise causal conv (k=4) + silu
__global__ __launch_bounds__(256) void conv_silu_kernel(const float* __restrict__ xz,
                                                        const float* __restrict__ cw,
                                                        const float* __restrict__ cb,
                                                        float* __restrict__ xc) {
    int idx = blockIdx.x * 256 + threadIdx.x;   // l*DI + d
    int l = idx >> 11;
    int d = idx & (DI - 1);
    float s = cb[d];
#pragma unroll
    for (int k = 0; k < DCONV; ++k) {
        int t = l - (DCONV - 1) + k;
        if (t >= 0) s += cw[d * DCONV + k] * xz[(size_t)t * (2 * DI) + d];
    }
    xc[idx] = s / (1.f + expf(-s));   // silu
}

// ---------------- x_dbl[l, 0..47] = xc[l,:] @ W_x[j,:]
__global__ __launch_bounds__(256) void xdbl_kernel(const float* __restrict__ xc,
                                                   const float* __restrict__ Wx,
                                                   float* __restrict__ xdbl) {
    __shared__ float row[DI];
    const int l = blockIdx.x;
    for (int i = threadIdx.x; i < DI / 4; i += 256)
        *(float4*)(row + i * 4) = *(const float4*)(xc + (size_t)l * DI + i * 4);
    __syncthreads();
    const int wave = threadIdx.x >> 6;
    const int lane = threadIdx.x & 63;
    for (int j = wave; j < RNK + 2 * NST; j += 4) {
        float s = 0.f;
        for (int k = lane; k < DI; k += 64) s += row[k] * Wx[(size_t)j * DI + k];
#pragma unroll
        for (int off = 32; off; off >>= 1) s += __shfl_down(s, off);
        if (lane == 0) xdbl[l * 48 + j] = s;
    }
}

// ---------------- delta[l,d] = softplus(xdbl[l,:16] @ W_dt[d,:] + b_dt[d])
__global__ __launch_bounds__(256) void delta_kernel(const float* __restrict__ xdbl,
                                                    const float* __restrict__ Wdt,
                                                    const float* __restrict__ bdt,
                                                    float* __restrict__ delta) {
    int idx = blockIdx.x * 256 + threadIdx.x;
    int l = idx >> 11;
    int d = idx & (DI - 1);
    float s = bdt[d];
#pragma unroll
    for (int r = 0; r < RNK; ++r) s += xdbl[l * 48 + r] * Wdt[d * RNK + r];
    delta[idx] = fmaxf(s, 0.f) + log1pf(expf(-fabsf(s)));   // jax softplus
}

// ---------------- scan phase A: per-chunk local scan + carry multiplier
__global__ __launch_bounds__(256) void scan_a(const float* __restrict__ delta,
                                              const float* __restrict__ xc,
                                              const float* __restrict__ xdbl,
                                              const float* __restrict__ A_log,
                                              float* __restrict__ hloc,
                                              float* __restrict__ aexp) {
    int idx = blockIdx.x * 256 + threadIdx.x;  // c*DI*NST + d*NST + n
    int n = idx & (NST - 1);
    int d = (idx >> 4) & (DI - 1);
    int c = idx >> 15;
    float Adn = -expf(A_log[d * NST + n]);
    float h = 0.f, dsum = 0.f;
    int t0 = c * TCH;
    for (int t = t0; t < t0 + TCH; ++t) {
        float dl = delta[(size_t)t * DI + d];
        float u  = xc[(size_t)t * DI + d];
        float b  = xdbl[t * 48 + RNK + n];
        dsum += dl;
        h = expf(Adn * dl) * h + dl * b * u;
    }
    hloc[idx] = h;
    aexp[idx] = expf(Adn * dsum);
}

// ---------------- scan phase B: sequential combine over chunks
__global__ __launch_bounds__(256) void scan_b(const float* __restrict__ hloc,
                                              const float* __restrict__ aexp,
                                              float* __restrict__ hinit) {
    int idx = blockIdx.x * 256 + threadIdx.x;   // d*NST+n, DI*NST threads
    float h = 0.f;
    for (int c = 0; c < CCH; ++c) {
        hinit[c * (DI * NST) + idx] = h;
        h = aexp[c * (DI * NST) + idx] * h + hloc[c * (DI * NST) + idx];
    }
}

// ---------------- scan phase C: replay with correct init, reduce over n, write y
__global__ __launch_bounds__(256) void scan_c(const float* __restrict__ delta,
                                              const float* __restrict__ xc,
                                              const float* __restrict__ xdbl,
                                              const float* __restrict__ A_log,
                                              const float* __restrict__ hinit,
                                              float* __restrict__ y /* stride 2*DI */) {
    int idx = blockIdx.x * 256 + threadIdx.x;  // c*DI*NST + d*NST + n
    int n = idx & (NST - 1);
    int d = (idx >> 4) & (DI - 1);
    int c = idx >> 15;
    float Adn = -expf(A_log[d * NST + n]);
    float h = hinit[idx];
    int t0 = c * TCH;
    for (int t = t0; t < t0 + TCH; ++t) {
        float dl = delta[(size_t)t * DI + d];
        float u  = xc[(size_t)t * DI + d];
        float b  = xdbl[t * 48 + RNK + n];
        float ct = xdbl[t * 48 + RNK + NST + n];
        h = expf(Adn * dl) * h + dl * b * u;
        float p = h * ct;
        p += __shfl_xor(p, 1);
        p += __shfl_xor(p, 2);
        p += __shfl_xor(p, 4);
        p += __shfl_xor(p, 8);
        if (n == 0) y[(size_t)t * (2 * DI) + d] = p;
    }
}

// ---------------- gate: g = (y + xc*D) * silu(res)
__global__ __launch_bounds__(256) void gate_kernel(const float* __restrict__ xz, // y in [:, :DI], res in [:, DI:]
                                                   const float* __restrict__ xc,
                                                   const float* __restrict__ Dp,
                                                   float* __restrict__ g) {
    int idx = blockIdx.x * 256 + threadIdx.x;
    int l = idx >> 11;
    int d = idx & (DI - 1);
    float yv = xz[(size_t)l * (2 * DI) + d];
    float rv = xz[(size_t)l * (2 * DI) + DI + d];
    g[idx] = (yv + xc[idx] * Dp[d]) * (rv / (1.f + expf(-rv)));
}

extern "C" void kernel_launch(void* const* d_in, const int* in_sizes, int n_in,
                              void* d_out, int out_size, void* d_ws, size_t ws_size,
                              hipStream_t stream) {
    const float* x      = (const float*)d_in[0];
    const float* W_in   = (const float*)d_in[1];
    const float* conv_w = (const float*)d_in[2];
    const float* conv_b = (const float*)d_in[3];
    const float* W_x    = (const float*)d_in[4];
    const float* W_dt   = (const float*)d_in[5];
    const float* b_dt   = (const float*)d_in[6];
    const float* A_log  = (const float*)d_in[7];
    const float* Dp     = (const float*)d_in[8];
    const float* W_out  = (const float*)d_in[9];
    float* out = (float*)d_out;

    float* ws = (float*)d_ws;
    // workspace layout (floats)
    const size_t XZ_OFF    = 0;                                // L*2*DI
    const size_t XC_OFF    = XZ_OFF + (size_t)L * 2 * DI;
    const size_t DELTA_OFF = XC_OFF + (size_t)L * DI;
    const size_t XDBL_OFF  = DELTA_OFF + (size_t)L * DI;
    const size_t HLOC_OFF  = XDBL_OFF + 131072;
    const size_t AEXP_OFF  = HLOC_OFF + (size_t)CCH * DI * NST;
    const size_t HINIT_OFF = AEXP_OFF + (size_t)CCH * DI * NST;

    float* xz    = ws + XZ_OFF;
    float* xc    = ws + XC_OFF;
    float* delta = ws + DELTA_OFF;
    float* xdbl  = ws + XDBL_OFF;
    float* hloc  = ws + HLOC_OFF;
    float* aexp  = ws + AEXP_OFF;
    float* hinit = ws + HINIT_OFF;
    float* g     = delta;   // reuse delta buffer after scan
    float* y     = xz;      // y written into xz[:, :DI] (raw conv input is dead)

    // 1. in_proj: xz[L, 2*DI] = x[L,DM] @ W_in[2*DI,DM]^T   (bf16x3 MFMA)
    {
        dim3 grid(L / 128, (2 * DI) / 128);
        gemm_bt3<128, 128><<<grid, 256, 0, stream>>>(x, W_in, xz, L, 2 * DI, DM);
    }
    // 2. conv + silu -> xc
    conv_silu_kernel<<<(L * DI) / 256, 256, 0, stream>>>(xz, conv_w, conv_b, xc);
    // 3. x_dbl
    xdbl_kernel<<<L, 256, 0, stream>>>(xc, W_x, xdbl);
    // 4. delta
    delta_kernel<<<(L * DI) / 256, 256, 0, stream>>>(xdbl, W_dt, b_dt, delta);
    // 5. scan phase A
    scan_a<<<(CCH * DI * NST) / 256, 256, 0, stream>>>(delta, xc, xdbl, A_log, hloc, aexp);
    // 6. scan phase B
    scan_b<<<(DI * NST) / 256, 256, 0, stream>>>(hloc, aexp, hinit);
    // 7. scan phase C -> y (into xz first half)
    scan_c<<<(CCH * DI * NST) / 256, 256, 0, stream>>>(delta, xc, xdbl, A_log, hinit, y);
    // 8. gate -> g (reuses delta buffer)
    gate_kernel<<<(L * DI) / 256, 256, 0, stream>>>(xz, xc, Dp, g);
    // 9. out_proj: out[L,DM] = g[L,DI] @ W_out[DM,DI]^T  (64-row tiles -> 256 blocks)
    {
        dim3 grid(L / 64, DM / 128);
        gemm_bt3<64, 128><<<grid, 256, 0, stream>>>(g, W_out, out, L, DM, DI);
    }
}

// Round 3
// 340.952 us; speedup vs baseline: 2.3596x; 1.3269x over previous
//
#include <hip/hip_runtime.h>
#include <hip/hip_bf16.h>
#include <math.h>

// Problem dims (compile-time)
#define L     2048
#define DM    1024
#define DI    2048
#define DCONV 4
#define RNK   16
#define NST   16
#define CCH   32          // number of scan chunks
#define TCH   (L / CCH)   // steps per chunk = 64

#define XKC   16          // xdbl split-K chunks
#define XKK   (DI / XKC)  // 128 = 4 k-steps of 32

typedef __attribute__((ext_vector_type(8))) short bf16x8;   // 8 bf16 in 4 VGPRs
typedef __attribute__((ext_vector_type(4))) float f32x4;
typedef __attribute__((ext_vector_type(4))) unsigned short u16x4;

// ---- fp32 -> bf16 (RNE) split helpers ----
__device__ __forceinline__ unsigned short bfh(float f) {
    unsigned u = __float_as_uint(f);
    unsigned r = u + 0x7FFFu + ((u >> 16) & 1u);
    return (unsigned short)(r >> 16);
}
__device__ __forceinline__ float bf2f(unsigned short h) {
    return __uint_as_float(((unsigned)h) << 16);
}

// Swizzled LDS byte offset for a [R][32]-bf16 tile (row = 64 B).
__device__ __forceinline__ int swz_byte(int row, int q) {
    return row * 64 + ((q ^ ((row >> 1) & 3)) << 4);
}

// Stage an R x 32 fp32 tile into hi/lo bf16 LDS tiles (swizzled).
template<int R>
__device__ __forceinline__ void stage_tile(const float* __restrict__ src, int K, int k0,
                                           unsigned short* sh, unsigned short* sl, int tid) {
#pragma unroll
    for (int c0 = 0; c0 < R * 8; c0 += 256) {
        int c = c0 + tid;
        bool ok = (R * 8 % 256 == 0) || (c < R * 8);
        if (ok) {
            int row = c >> 3, cc = c & 7;              // cc: which float4 of the row
            float4 v = *(const float4*)(src + (size_t)row * K + k0 + cc * 4);
            unsigned short hx = bfh(v.x), hy = bfh(v.y), hz = bfh(v.z), hw = bfh(v.w);
            unsigned short lx = bfh(v.x - bf2f(hx));
            unsigned short ly = bfh(v.y - bf2f(hy));
            unsigned short lz = bfh(v.z - bf2f(hz));
            unsigned short lw = bfh(v.w - bf2f(hw));
            int byte = swz_byte(row, cc >> 1) + ((cc & 1) << 3);
            u16x4 hv = {hx, hy, hz, hw};
            u16x4 lv = {lx, ly, lz, lw};
            *(u16x4*)((char*)sh + byte) = hv;
            *(u16x4*)((char*)sl + byte) = lv;
        }
    }
}

__device__ __forceinline__ bf16x8 rdfrag(const unsigned short* base, int row, int q) {
    return *(const bf16x8*)((const char*)base + swz_byte(row, q));
}

// C[M,N] = A[M,K] * B[N,K]^T in fp32-via-3xbf16-MFMA.
template<int BM, int BN>
__global__ __launch_bounds__(256) void gemm_bt3(const float* __restrict__ A,
                                                const float* __restrict__ B,
                                                float* __restrict__ C,
                                                int M, int N, int K) {
    __shared__ __align__(16) unsigned short Ah[BM * 32];
    __shared__ __align__(16) unsigned short Al[BM * 32];
    __shared__ __align__(16) unsigned short Bh[BN * 32];
    __shared__ __align__(16) unsigned short Bl[BN * 32];

    const int tid = threadIdx.x;
    const int bm = blockIdx.x * BM, bn = blockIdx.y * BN;
    const int l = tid & 63, wv = tid >> 6;
    const int wr = (wv >> 1) * (BM / 2), wc = (wv & 1) * (BN / 2);
    constexpr int MR = BM / 32, NR = BN / 32;
    const int fr = l & 15, q = l >> 4;

    f32x4 acc[MR][NR];
#pragma unroll
    for (int m = 0; m < MR; ++m)
#pragma unroll
        for (int n = 0; n < NR; ++n) acc[m][n] = (f32x4){0.f, 0.f, 0.f, 0.f};

    const float* Ab = A + (size_t)bm * K;
    const float* Bb = B + (size_t)bn * K;

    for (int k0 = 0; k0 < K; k0 += 32) {
        stage_tile<BM>(Ab, K, k0, Ah, Al, tid);
        stage_tile<BN>(Bb, K, k0, Bh, Bl, tid);
        __syncthreads();

        bf16x8 ah[MR], av[MR], bh[NR], bv[NR];
#pragma unroll
        for (int m = 0; m < MR; ++m) {
            int row = wr + m * 16 + fr;
            ah[m] = rdfrag(Ah, row, q);
            av[m] = rdfrag(Al, row, q);
        }
#pragma unroll
        for (int n = 0; n < NR; ++n) {
            int row = wc + n * 16 + fr;
            bh[n] = rdfrag(Bh, row, q);
            bv[n] = rdfrag(Bl, row, q);
        }
#pragma unroll
        for (int m = 0; m < MR; ++m)
#pragma unroll
            for (int n = 0; n < NR; ++n) {
                acc[m][n] = __builtin_amdgcn_mfma_f32_16x16x32_bf16(av[m], bh[n], acc[m][n], 0, 0, 0);
                acc[m][n] = __builtin_amdgcn_mfma_f32_16x16x32_bf16(ah[m], bv[n], acc[m][n], 0, 0, 0);
                acc[m][n] = __builtin_amdgcn_mfma_f32_16x16x32_bf16(ah[m], bh[n], acc[m][n], 0, 0, 0);
            }
        __syncthreads();
    }

    // C/D layout: col = lane&15, row = (lane>>4)*4 + reg  [m89/m91]
#pragma unroll
    for (int m = 0; m < MR; ++m)
#pragma unroll
        for (int n = 0; n < NR; ++n) {
            int row0 = bm + wr + m * 16 + q * 4;
            int col  = bn + wc + n * 16 + fr;
#pragma unroll
            for (int r = 0; r < 4; ++r)
                C[(size_t)(row0 + r) * N + col] = acc[m][n][r];
        }
}

// ---------------- xdbl split-K MFMA: partial[kc][128 rows][48] = xc_tile @ W_x^T (k-chunk)
__global__ __launch_bounds__(256) void xdbl_mfma(const float* __restrict__ xc,
                                                 const float* __restrict__ Wx,
                                                 float* __restrict__ part) {
    __shared__ __align__(16) unsigned short Ah[128 * 32];
    __shared__ __align__(16) unsigned short Al[128 * 32];
    __shared__ __align__(16) unsigned short Bh[48 * 32];
    __shared__ __align__(16) unsigned short Bl[48 * 32];

    const int tid = threadIdx.x;
    const int bm = blockIdx.x * 128;       // row tile
    const int kc = blockIdx.y;             // k-chunk
    const int l = tid & 63, wv = tid >> 6;
    const int wr = wv * 32;                // each wave: 32 rows x 48 cols
    const int fr = l & 15, q = l >> 4;

    f32x4 acc[2][3];
#pragma unroll
    for (int m = 0; m < 2; ++m)
#pragma unroll
        for (int n = 0; n < 3; ++n) acc[m][n] = (f32x4){0.f, 0.f, 0.f, 0.f};

    const float* Ab = xc + (size_t)bm * DI;

    for (int ks = 0; ks < XKK; ks += 32) {
        int k0 = kc * XKK + ks;
        stage_tile<128>(Ab, DI, k0, Ah, Al, tid);
        stage_tile<48>(Wx, DI, k0, Bh, Bl, tid);
        __syncthreads();

        bf16x8 ah[2], av[2], bh[3], bv[3];
#pragma unroll
        for (int m = 0; m < 2; ++m) {
            int row = wr + m * 16 + fr;
            ah[m] = rdfrag(Ah, row, q);
            av[m] = rdfrag(Al, row, q);
        }
#pragma unroll
        for (int n = 0; n < 3; ++n) {
            int row = n * 16 + fr;
            bh[n] = rdfrag(Bh, row, q);
            bv[n] = rdfrag(Bl, row, q);
        }
#pragma unroll
        for (int m = 0; m < 2; ++m)
#pragma unroll
            for (int n = 0; n < 3; ++n) {
                acc[m][n] = __builtin_amdgcn_mfma_f32_16x16x32_bf16(av[m], bh[n], acc[m][n], 0, 0, 0);
                acc[m][n] = __builtin_amdgcn_mfma_f32_16x16x32_bf16(ah[m], bv[n], acc[m][n], 0, 0, 0);
                acc[m][n] = __builtin_amdgcn_mfma_f32_16x16x32_bf16(ah[m], bh[n], acc[m][n], 0, 0, 0);
            }
        __syncthreads();
    }

#pragma unroll
    for (int m = 0; m < 2; ++m)
#pragma unroll
        for (int n = 0; n < 3; ++n) {
            int row0 = bm + wr + m * 16 + q * 4;
            int col  = n * 16 + fr;
#pragma unroll
            for (int r = 0; r < 4; ++r)
                part[(size_t)kc * (L * 48) + (size_t)(row0 + r) * 48 + col] = acc[m][n][r];
        }
}

__global__ __launch_bounds__(256) void xdbl_reduce(const float* __restrict__ part,
                                                   float* __restrict__ xdbl) {
    int i = blockIdx.x * 256 + threadIdx.x;   // 0 .. L*48
    float s = 0.f;
#pragma unroll
    for (int kc = 0; kc < XKC; ++kc) s += part[(size_t)kc * (L * 48) + i];
    xdbl[i] = s;
}

// ---------------- depthwise causal conv (k=4) + silu, float4
__global__ __launch_bounds__(256) void conv_silu_kernel(const float* __restrict__ xz,
                                                        const float* __restrict__ cw,
                                                        const float* __restrict__ cb,
                                                        float* __restrict__ xc) {
    int idx = blockIdx.x * 256 + threadIdx.x;   // l*(DI/4) + d4
    int l = idx >> 9;
    int d = (idx & 511) << 2;
    float4 s = *(const float4*)(cb + d);
    float4 w0 = *(const float4*)(cw + (d + 0) * 4);
    float4 w1 = *(const float4*)(cw + (d + 1) * 4);
    float4 w2 = *(const float4*)(cw + (d + 2) * 4);
    float4 w3 = *(const float4*)(cw + (d + 3) * 4);
#pragma unroll
    for (int k = 0; k < DCONV; ++k) {
        int t = l - (DCONV - 1) + k;
        if (t >= 0) {
            float4 xv = *(const float4*)(xz + (size_t)t * (2 * DI) + d);
            s.x += ((const float*)&w0)[k] * xv.x;
            s.y += ((const float*)&w1)[k] * xv.y;
            s.z += ((const float*)&w2)[k] * xv.z;
            s.w += ((const float*)&w3)[k] * xv.w;
        }
    }
    float4 o;
    o.x = s.x / (1.f + expf(-s.x));
    o.y = s.y / (1.f + expf(-s.y));
    o.z = s.z / (1.f + expf(-s.z));
    o.w = s.w / (1.f + expf(-s.w));
    *(float4*)(xc + (size_t)l * DI + d) = o;
}

// ---------------- delta[l,d] = softplus(xdbl[l,:16] @ W_dt[d,:] + b_dt[d])
__global__ __launch_bounds__(256) void delta_kernel(const float* __restrict__ xdbl,
                                                    const float* __restrict__ Wdt,
                                                    const float* __restrict__ bdt,
                                                    float* __restrict__ delta) {
    int idx = blockIdx.x * 256 + threadIdx.x;
    int l = idx >> 11;
    int d = idx & (DI - 1);
    float s = bdt[d];
    const float4* xr = (const float4*)(xdbl + l * 48);
    const float4* wr = (const float4*)(Wdt + d * RNK);
#pragma unroll
    for (int c = 0; c < 4; ++c) {
        float4 xv = xr[c], wv = wr[c];
        s += xv.x * wv.x + xv.y * wv.y + xv.z * wv.z + xv.w * wv.w;
    }
    delta[idx] = fmaxf(s, 0.f) + log1pf(expf(-fabsf(s)));   // jax softplus
}

// ---------------- scan phase A: per-chunk local scan + carry multiplier
__global__ __launch_bounds__(256) void scan_a(const float* __restrict__ delta,
                                              const float* __restrict__ xc,
                                              const float* __restrict__ xdbl,
                                              const float* __restrict__ A_log,
                                              float* __restrict__ hloc,
                                              float* __restrict__ aexp) {
    int idx = blockIdx.x * 256 + threadIdx.x;  // c*DI*NST + d*NST + n
    int n = idx & (NST - 1);
    int d = (idx >> 4) & (DI - 1);
    int c = idx >> 15;
    float Adn = -expf(A_log[d * NST + n]);
    float h = 0.f, dsum = 0.f;
    int t0 = c * TCH;
    for (int t = t0; t < t0 + TCH; ++t) {
        float dl = delta[(size_t)t * DI + d];
        float u  = xc[(size_t)t * DI + d];
        float b  = xdbl[t * 48 + RNK + n];
        dsum += dl;
        h = expf(Adn * dl) * h + dl * b * u;
    }
    hloc[idx] = h;
    aexp[idx] = expf(Adn * dsum);
}

// ---------------- scan phase B: sequential combine over chunks
__global__ __launch_bounds__(256) void scan_b(const float* __restrict__ hloc,
                                              const float* __restrict__ aexp,
                                              float* __restrict__ hinit) {
    int idx = blockIdx.x * 256 + threadIdx.x;   // d*NST+n, DI*NST threads
    float h = 0.f;
    for (int c = 0; c < CCH; ++c) {
        hinit[c * (DI * NST) + idx] = h;
        h = aexp[c * (DI * NST) + idx] * h + hloc[c * (DI * NST) + idx];
    }
}

// ---------------- scan phase C: replay with correct init, reduce over n, write y
__global__ __launch_bounds__(256) void scan_c(const float* __restrict__ delta,
                                              const float* __restrict__ xc,
                                              const float* __restrict__ xdbl,
                                              const float* __restrict__ A_log,
                                              const float* __restrict__ hinit,
                                              float* __restrict__ y /* stride 2*DI */) {
    int idx = blockIdx.x * 256 + threadIdx.x;  // c*DI*NST + d*NST + n
    int n = idx & (NST - 1);
    int d = (idx >> 4) & (DI - 1);
    int c = idx >> 15;
    float Adn = -expf(A_log[d * NST + n]);
    float h = hinit[idx];
    int t0 = c * TCH;
    for (int t = t0; t < t0 + TCH; ++t) {
        float dl = delta[(size_t)t * DI + d];
        float u  = xc[(size_t)t * DI + d];
        float b  = xdbl[t * 48 + RNK + n];
        float ct = xdbl[t * 48 + RNK + NST + n];
        h = expf(Adn * dl) * h + dl * b * u;
        float p = h * ct;
        p += __shfl_xor(p, 1);
        p += __shfl_xor(p, 2);
        p += __shfl_xor(p, 4);
        p += __shfl_xor(p, 8);
        if (n == 0) y[(size_t)t * (2 * DI) + d] = p;
    }
}

// ---------------- gate: g = (y + xc*D) * silu(res), float4
__global__ __launch_bounds__(256) void gate_kernel(const float* __restrict__ xz, // y in [:, :DI], res in [:, DI:]
                                                   const float* __restrict__ xc,
                                                   const float* __restrict__ Dp,
                                                   float* __restrict__ g) {
    int idx = blockIdx.x * 256 + threadIdx.x;   // l*(DI/4) + d4
    int l = idx >> 9;
    int d = (idx & 511) << 2;
    float4 yv = *(const float4*)(xz + (size_t)l * (2 * DI) + d);
    float4 rv = *(const float4*)(xz + (size_t)l * (2 * DI) + DI + d);
    float4 xv = *(const float4*)(xc + (size_t)l * DI + d);
    float4 dv = *(const float4*)(Dp + d);
    float4 o;
    o.x = (yv.x + xv.x * dv.x) * (rv.x / (1.f + expf(-rv.x)));
    o.y = (yv.y + xv.y * dv.y) * (rv.y / (1.f + expf(-rv.y)));
    o.z = (yv.z + xv.z * dv.z) * (rv.z / (1.f + expf(-rv.z)));
    o.w = (yv.w + xv.w * dv.w) * (rv.w / (1.f + expf(-rv.w)));
    *(float4*)(g + (size_t)l * DI + d) = o;
}

extern "C" void kernel_launch(void* const* d_in, const int* in_sizes, int n_in,
                              void* d_out, int out_size, void* d_ws, size_t ws_size,
                              hipStream_t stream) {
    const float* x      = (const float*)d_in[0];
    const float* W_in   = (const float*)d_in[1];
    const float* conv_w = (const float*)d_in[2];
    const float* conv_b = (const float*)d_in[3];
    const float* W_x    = (const float*)d_in[4];
    const float* W_dt   = (const float*)d_in[5];
    const float* b_dt   = (const float*)d_in[6];
    const float* A_log  = (const float*)d_in[7];
    const float* Dp     = (const float*)d_in[8];
    const float* W_out  = (const float*)d_in[9];
    float* out = (float*)d_out;

    float* ws = (float*)d_ws;
    // workspace layout (floats)
    const size_t XZ_OFF    = 0;                                // L*2*DI
    const size_t XC_OFF    = XZ_OFF + (size_t)L * 2 * DI;
    const size_t DELTA_OFF = XC_OFF + (size_t)L * DI;
    const size_t XDBL_OFF  = DELTA_OFF + (size_t)L * DI;
    const size_t HLOC_OFF  = XDBL_OFF + 131072;
    const size_t AEXP_OFF  = HLOC_OFF + (size_t)CCH * DI * NST;
    const size_t HINIT_OFF = AEXP_OFF + (size_t)CCH * DI * NST;

    float* xz    = ws + XZ_OFF;
    float* xc    = ws + XC_OFF;
    float* delta = ws + DELTA_OFF;
    float* xdbl  = ws + XDBL_OFF;
    float* hloc  = ws + HLOC_OFF;
    float* aexp  = ws + AEXP_OFF;
    float* hinit = ws + HINIT_OFF;
    float* g     = delta;   // reuse delta buffer after scan
    float* y     = xz;      // y written into xz[:, :DI] (raw conv input is dead)
    float* part  = hloc;    // xdbl partials (16*L*48 = 1.57M floats) live in
                            // hloc+aexp (2.1M floats) — dead until scan_a.

    // 1. in_proj: xz[L, 2*DI] = x[L,DM] @ W_in[2*DI,DM]^T   (bf16x3 MFMA)
    {
        dim3 grid(L / 128, (2 * DI) / 128);
        gemm_bt3<128, 128><<<grid, 256, 0, stream>>>(x, W_in, xz, L, 2 * DI, DM);
    }
    // 2. conv + silu -> xc
    conv_silu_kernel<<<(L * DI / 4) / 256, 256, 0, stream>>>(xz, conv_w, conv_b, xc);
    // 3. x_dbl: split-K MFMA + reduce
    {
        dim3 grid(L / 128, XKC);
        xdbl_mfma<<<grid, 256, 0, stream>>>(xc, W_x, part);
        xdbl_reduce<<<(L * 48) / 256, 256, 0, stream>>>(part, xdbl);
    }
    // 4. delta
    delta_kernel<<<(L * DI) / 256, 256, 0, stream>>>(xdbl, W_dt, b_dt, delta);
    // 5. scan phase A
    scan_a<<<(CCH * DI * NST) / 256, 256, 0, stream>>>(delta, xc, xdbl, A_log, hloc, aexp);
    // 6. scan phase B
    scan_b<<<(DI * NST) / 256, 256, 0, stream>>>(hloc, aexp, hinit);
    // 7. scan phase C -> y (into xz first half)
    scan_c<<<(CCH * DI * NST) / 256, 256, 0, stream>>>(delta, xc, xdbl, A_log, hinit, y);
    // 8. gate -> g (reuses delta buffer)
    gate_kernel<<<(L * DI / 4) / 256, 256, 0, stream>>>(xz, xc, Dp, g);
    // 9. out_proj: out[L,DM] = g[L,DI] @ W_out[DM,DI]^T  (64-row tiles -> 256 blocks)
    {
        dim3 grid(L / 64, DM / 128);
        gemm_bt3<64, 128><<<grid, 256, 0, stream>>>(g, W_out, out, L, DM, DI);
    }
}

// Round 4
// 308.159 us; speedup vs baseline: 2.6106x; 1.1064x over previous
//
#include <hip/hip_runtime.h>
#include <hip/hip_bf16.h>
#include <math.h>

// Problem dims (compile-time)
#define L     2048
#define DM    1024
#define DI    2048
#define DCONV 4
#define RNK   16
#define NST   16
#define CCH   32          // number of scan chunks
#define TCH   (L / CCH)   // steps per chunk = 64

#define XKC   16          // xdbl split-K chunks
#define XKK   (DI / XKC)  // 128 = 4 k-steps of 32

typedef __attribute__((ext_vector_type(8))) short bf16x8;   // 8 bf16 in 4 VGPRs
typedef __attribute__((ext_vector_type(4))) float f32x4;
typedef __attribute__((ext_vector_type(4))) unsigned short u16x4;
typedef __attribute__((ext_vector_type(8))) unsigned short u16x8;

// ---- fp32 -> bf16 (RNE) split helpers ----
__device__ __forceinline__ unsigned short bfh(float f) {
    unsigned u = __float_as_uint(f);
    unsigned r = u + 0x7FFFu + ((u >> 16) & 1u);
    return (unsigned short)(r >> 16);
}
__device__ __forceinline__ float bf2f(unsigned short h) {
    return __uint_as_float(((unsigned)h) << 16);
}

// Swizzled LDS byte offset for a [R][32]-bf16 tile (row = 64 B).
// Chunk q (16B) XORed with (row>>1)&3 -> fragment reads are conflict-free
// (verified: SQ_LDS_BANK_CONFLICT == 0 in round 3).
__device__ __forceinline__ int swz_byte(int row, int q) {
    return row * 64 + ((q ^ ((row >> 1) & 3)) << 4);
}

__device__ __forceinline__ bf16x8 rdfrag(const unsigned short* base, int row, int q) {
    return *(const bf16x8*)((const char*)base + swz_byte(row, q));
}

// ---------------- split fp32 array into bf16 hi/lo planes (once per buffer)
__global__ __launch_bounds__(256) void split_kernel(const float* __restrict__ in,
                                                    unsigned short* __restrict__ h,
                                                    unsigned short* __restrict__ l) {
    int i = blockIdx.x * 256 + threadIdx.x;
    float4 v = ((const float4*)in)[i];
    unsigned short hx = bfh(v.x), hy = bfh(v.y), hz = bfh(v.z), hw = bfh(v.w);
    u16x4 hv = {hx, hy, hz, hw};
    u16x4 lv = {bfh(v.x - bf2f(hx)), bfh(v.y - bf2f(hy)),
                bfh(v.z - bf2f(hz)), bfh(v.w - bf2f(hw))};
    ((u16x4*)h)[i] = hv;
    ((u16x4*)l)[i] = lv;
}

// Simple (non-pipelined) plane staging for the small xdbl GEMM.
template<int R>
__device__ __forceinline__ void stage_pl(const unsigned short* __restrict__ gh,
                                         const unsigned short* __restrict__ gl,
                                         int ldK, int k0,
                                         unsigned short* sh, unsigned short* sl, int tid) {
#pragma unroll
    for (int c0 = 0; c0 < R * 4; c0 += 256) {
        int c = c0 + tid;
        if ((R * 4 % 256 == 0) || c < R * 4) {
            int row = c >> 2, q = c & 3;
            size_t off = (size_t)row * ldK + k0 + q * 8;
            u16x8 hv = *(const u16x8*)(gh + off);
            u16x8 lv = *(const u16x8*)(gl + off);
            int byte = swz_byte(row, q);
            *(u16x8*)((char*)sh + byte) = hv;
            *(u16x8*)((char*)sl + byte) = lv;
        }
    }
}

// C[M,N] (+z*M*N) = A[M, kStart:kStart+kLen] * B[N, ...]^T, planes pre-split.
// T14 pipeline: ds_write tile k, then issue global loads for k+1, then MFMA.
template<int BM, int BN>
__global__ __launch_bounds__(256) void gemm_pl(const unsigned short* __restrict__ Agh,
                                               const unsigned short* __restrict__ Agl,
                                               const unsigned short* __restrict__ Bgh,
                                               const unsigned short* __restrict__ Bgl,
                                               float* __restrict__ C,
                                               int M, int N, int K, int kLen) {
    __shared__ __align__(16) unsigned short Ah[BM * 32];
    __shared__ __align__(16) unsigned short Al[BM * 32];
    __shared__ __align__(16) unsigned short Bh[BN * 32];
    __shared__ __align__(16) unsigned short Bl[BN * 32];

    const int tid = threadIdx.x;
    const int bm = blockIdx.x * BM, bn = blockIdx.y * BN;
    const int kStart = blockIdx.z * kLen;
    const int l = tid & 63, wv = tid >> 6;
    const int wr = (wv >> 1) * (BM / 2), wc = (wv & 1) * (BN / 2);
    constexpr int MR = BM / 32, NR = BN / 32;
    const int fr = l & 15, q = l >> 4;

    constexpr int CA = (BM * 4) / 256;   // 16B chunks per thread, per A plane
    constexpr int CB = (BN * 4) / 256;

    u16x8 rAh[CA], rAl[CA], rBh[CB], rBl[CB];

    f32x4 acc[MR][NR];
#pragma unroll
    for (int m = 0; m < MR; ++m)
#pragma unroll
        for (int n = 0; n < NR; ++n) acc[m][n] = (f32x4){0.f, 0.f, 0.f, 0.f};

    // prologue: load tile 0
#pragma unroll
    for (int c = 0; c < CA; ++c) {
        int cc = c * 256 + tid, row = cc >> 2, qq = cc & 3;
        size_t off = (size_t)(bm + row) * K + kStart + qq * 8;
        rAh[c] = *(const u16x8*)(Agh + off);
        rAl[c] = *(const u16x8*)(Agl + off);
    }
#pragma unroll
    for (int c = 0; c < CB; ++c) {
        int cc = c * 256 + tid, row = cc >> 2, qq = cc & 3;
        size_t off = (size_t)(bn + row) * K + kStart + qq * 8;
        rBh[c] = *(const u16x8*)(Bgh + off);
        rBl[c] = *(const u16x8*)(Bgl + off);
    }

    for (int ks = 0; ks < kLen; ks += 32) {
        // write staged regs to LDS (waits vmcnt on the loads issued last iter)
#pragma unroll
        for (int c = 0; c < CA; ++c) {
            int cc = c * 256 + tid, row = cc >> 2, qq = cc & 3;
            int byte = swz_byte(row, qq);
            *(u16x8*)((char*)Ah + byte) = rAh[c];
            *(u16x8*)((char*)Al + byte) = rAl[c];
        }
#pragma unroll
        for (int c = 0; c < CB; ++c) {
            int cc = c * 256 + tid, row = cc >> 2, qq = cc & 3;
            int byte = swz_byte(row, qq);
            *(u16x8*)((char*)Bh + byte) = rBh[c];
            *(u16x8*)((char*)Bl + byte) = rBl[c];
        }
        // issue next tile's loads; they complete under the MFMA phase
        if (ks + 32 < kLen) {
            int k1 = kStart + ks + 32;
#pragma unroll
            for (int c = 0; c < CA; ++c) {
                int cc = c * 256 + tid, row = cc >> 2, qq = cc & 3;
                size_t off = (size_t)(bm + row) * K + k1 + qq * 8;
                rAh[c] = *(const u16x8*)(Agh + off);
                rAl[c] = *(const u16x8*)(Agl + off);
            }
#pragma unroll
            for (int c = 0; c < CB; ++c) {
                int cc = c * 256 + tid, row = cc >> 2, qq = cc & 3;
                size_t off = (size_t)(bn + row) * K + k1 + qq * 8;
                rBh[c] = *(const u16x8*)(Bgh + off);
                rBl[c] = *(const u16x8*)(Bgl + off);
            }
        }
        __syncthreads();

        bf16x8 ah[MR], av[MR], bh[NR], bv[NR];
#pragma unroll
        for (int m = 0; m < MR; ++m) {
            int row = wr + m * 16 + fr;
            ah[m] = rdfrag(Ah, row, q);
            av[m] = rdfrag(Al, row, q);
        }
#pragma unroll
        for (int n = 0; n < NR; ++n) {
            int row = wc + n * 16 + fr;
            bh[n] = rdfrag(Bh, row, q);
            bv[n] = rdfrag(Bl, row, q);
        }
#pragma unroll
        for (int m = 0; m < MR; ++m)
#pragma unroll
            for (int n = 0; n < NR; ++n) {
                acc[m][n] = __builtin_amdgcn_mfma_f32_16x16x32_bf16(av[m], bh[n], acc[m][n], 0, 0, 0);
                acc[m][n] = __builtin_amdgcn_mfma_f32_16x16x32_bf16(ah[m], bv[n], acc[m][n], 0, 0, 0);
                acc[m][n] = __builtin_amdgcn_mfma_f32_16x16x32_bf16(ah[m], bh[n], acc[m][n], 0, 0, 0);
            }
        __syncthreads();
    }

    float* Cz = C + (size_t)blockIdx.z * M * N;
#pragma unroll
    for (int m = 0; m < MR; ++m)
#pragma unroll
        for (int n = 0; n < NR; ++n) {
            int row0 = bm + wr + m * 16 + q * 4;
            int col  = bn + wc + n * 16 + fr;
#pragma unroll
            for (int r = 0; r < 4; ++r)
                Cz[(size_t)(row0 + r) * N + col] = acc[m][n][r];
        }
}

// ---------------- xdbl split-K MFMA from planes
__global__ __launch_bounds__(256) void xdbl_mfma(const unsigned short* __restrict__ xch,
                                                 const unsigned short* __restrict__ xcl,
                                                 const unsigned short* __restrict__ Wxh,
                                                 const unsigned short* __restrict__ Wxl,
                                                 float* __restrict__ part) {
    __shared__ __align__(16) unsigned short Ah[128 * 32];
    __shared__ __align__(16) unsigned short Al[128 * 32];
    __shared__ __align__(16) unsigned short Bh[48 * 32];
    __shared__ __align__(16) unsigned short Bl[48 * 32];

    const int tid = threadIdx.x;
    const int bm = blockIdx.x * 128;
    const int kc = blockIdx.y;
    const int l = tid & 63, wv = tid >> 6;
    const int wr = wv * 32;
    const int fr = l & 15, q = l >> 4;

    f32x4 acc[2][3];
#pragma unroll
    for (int m = 0; m < 2; ++m)
#pragma unroll
        for (int n = 0; n < 3; ++n) acc[m][n] = (f32x4){0.f, 0.f, 0.f, 0.f};

    for (int ks = 0; ks < XKK; ks += 32) {
        int k0 = kc * XKK + ks;
        stage_pl<128>(xch + (size_t)bm * DI, xcl + (size_t)bm * DI, DI, k0, Ah, Al, tid);
        stage_pl<48>(Wxh, Wxl, DI, k0, Bh, Bl, tid);
        __syncthreads();

        bf16x8 ah[2], av[2], bh[3], bv[3];
#pragma unroll
        for (int m = 0; m < 2; ++m) {
            int row = wr + m * 16 + fr;
            ah[m] = rdfrag(Ah, row, q);
            av[m] = rdfrag(Al, row, q);
        }
#pragma unroll
        for (int n = 0; n < 3; ++n) {
            int row = n * 16 + fr;
            bh[n] = rdfrag(Bh, row, q);
            bv[n] = rdfrag(Bl, row, q);
        }
#pragma unroll
        for (int m = 0; m < 2; ++m)
#pragma unroll
            for (int n = 0; n < 3; ++n) {
                acc[m][n] = __builtin_amdgcn_mfma_f32_16x16x32_bf16(av[m], bh[n], acc[m][n], 0, 0, 0);
                acc[m][n] = __builtin_amdgcn_mfma_f32_16x16x32_bf16(ah[m], bv[n], acc[m][n], 0, 0, 0);
                acc[m][n] = __builtin_amdgcn_mfma_f32_16x16x32_bf16(ah[m], bh[n], acc[m][n], 0, 0, 0);
            }
        __syncthreads();
    }

#pragma unroll
    for (int m = 0; m < 2; ++m)
#pragma unroll
        for (int n = 0; n < 3; ++n) {
            int row0 = bm + wr + m * 16 + q * 4;
            int col  = n * 16 + fr;
#pragma unroll
            for (int r = 0; r < 4; ++r)
                part[(size_t)kc * (L * 48) + (size_t)(row0 + r) * 48 + col] = acc[m][n][r];
        }
}

__global__ __launch_bounds__(256) void xdbl_reduce(const float* __restrict__ part,
                                                   float* __restrict__ xdbl) {
    int i = blockIdx.x * 256 + threadIdx.x;
    float s = 0.f;
#pragma unroll
    for (int kc = 0; kc < XKC; ++kc) s += part[(size_t)kc * (L * 48) + i];
    xdbl[i] = s;
}

// ---------------- depthwise causal conv (k=4) + silu; writes fp32 xc + bf16 planes
__global__ __launch_bounds__(256) void conv_silu_kernel(const float* __restrict__ xz,
                                                        const float* __restrict__ cw,
                                                        const float* __restrict__ cb,
                                                        float* __restrict__ xc,
                                                        unsigned short* __restrict__ xch,
                                                        unsigned short* __restrict__ xcl) {
    int idx = blockIdx.x * 256 + threadIdx.x;   // l*(DI/4) + d4
    int l = idx >> 9;
    int d = (idx & 511) << 2;
    float4 s = *(const float4*)(cb + d);
    float4 w0 = *(const float4*)(cw + (d + 0) * 4);
    float4 w1 = *(const float4*)(cw + (d + 1) * 4);
    float4 w2 = *(const float4*)(cw + (d + 2) * 4);
    float4 w3 = *(const float4*)(cw + (d + 3) * 4);
#pragma unroll
    for (int k = 0; k < DCONV; ++k) {
        int t = l - (DCONV - 1) + k;
        if (t >= 0) {
            float4 xv = *(const float4*)(xz + (size_t)t * (2 * DI) + d);
            s.x += ((const float*)&w0)[k] * xv.x;
            s.y += ((const float*)&w1)[k] * xv.y;
            s.z += ((const float*)&w2)[k] * xv.z;
            s.w += ((const float*)&w3)[k] * xv.w;
        }
    }
    float4 o;
    o.x = s.x / (1.f + expf(-s.x));
    o.y = s.y / (1.f + expf(-s.y));
    o.z = s.z / (1.f + expf(-s.z));
    o.w = s.w / (1.f + expf(-s.w));
    *(float4*)(xc + (size_t)l * DI + d) = o;
    unsigned short hx = bfh(o.x), hy = bfh(o.y), hz = bfh(o.z), hw = bfh(o.w);
    u16x4 hv = {hx, hy, hz, hw};
    u16x4 lv = {bfh(o.x - bf2f(hx)), bfh(o.y - bf2f(hy)),
                bfh(o.z - bf2f(hz)), bfh(o.w - bf2f(hw))};
    *(u16x4*)(xch + (size_t)l * DI + d) = hv;
    *(u16x4*)(xcl + (size_t)l * DI + d) = lv;
}

// ---------------- delta[l,d] = softplus(xdbl[l,:16] @ W_dt[d,:] + b_dt[d])
__global__ __launch_bounds__(256) void delta_kernel(const float* __restrict__ xdbl,
                                                    const float* __restrict__ Wdt,
                                                    const float* __restrict__ bdt,
                                                    float* __restrict__ delta) {
    int idx = blockIdx.x * 256 + threadIdx.x;
    int l = idx >> 11;
    int d = idx & (DI - 1);
    float s = bdt[d];
    const float4* xr = (const float4*)(xdbl + l * 48);
    const float4* wr = (const float4*)(Wdt + d * RNK);
#pragma unroll
    for (int c = 0; c < 4; ++c) {
        float4 xv = xr[c], wv = wr[c];
        s += xv.x * wv.x + xv.y * wv.y + xv.z * wv.z + xv.w * wv.w;
    }
    delta[idx] = fmaxf(s, 0.f) + log1pf(expf(-fabsf(s)));   // jax softplus
}

// ---------------- scan phase A
__global__ __launch_bounds__(256) void scan_a(const float* __restrict__ delta,
                                              const float* __restrict__ xc,
                                              const float* __restrict__ xdbl,
                                              const float* __restrict__ A_log,
                                              float* __restrict__ hloc,
                                              float* __restrict__ aexp) {
    int idx = blockIdx.x * 256 + threadIdx.x;  // c*DI*NST + d*NST + n
    int n = idx & (NST - 1);
    int d = (idx >> 4) & (DI - 1);
    int c = idx >> 15;
    float Adn = -expf(A_log[d * NST + n]);
    float h = 0.f, dsum = 0.f;
    int t0 = c * TCH;
    for (int t = t0; t < t0 + TCH; ++t) {
        float dl = delta[(size_t)t * DI + d];
        float u  = xc[(size_t)t * DI + d];
        float b  = xdbl[t * 48 + RNK + n];
        dsum += dl;
        h = expf(Adn * dl) * h + dl * b * u;
    }
    hloc[idx] = h;
    aexp[idx] = expf(Adn * dsum);
}

// ---------------- scan phase B
__global__ __launch_bounds__(256) void scan_b(const float* __restrict__ hloc,
                                              const float* __restrict__ aexp,
                                              float* __restrict__ hinit) {
    int idx = blockIdx.x * 256 + threadIdx.x;
    float h = 0.f;
    for (int c = 0; c < CCH; ++c) {
        hinit[c * (DI * NST) + idx] = h;
        h = aexp[c * (DI * NST) + idx] * h + hloc[c * (DI * NST) + idx];
    }
}

// ---------------- scan phase C
__global__ __launch_bounds__(256) void scan_c(const float* __restrict__ delta,
                                              const float* __restrict__ xc,
                                              const float* __restrict__ xdbl,
                                              const float* __restrict__ A_log,
                                              const float* __restrict__ hinit,
                                              float* __restrict__ y /* stride 2*DI */) {
    int idx = blockIdx.x * 256 + threadIdx.x;
    int n = idx & (NST - 1);
    int d = (idx >> 4) & (DI - 1);
    int c = idx >> 15;
    float Adn = -expf(A_log[d * NST + n]);
    float h = hinit[idx];
    int t0 = c * TCH;
    for (int t = t0; t < t0 + TCH; ++t) {
        float dl = delta[(size_t)t * DI + d];
        float u  = xc[(size_t)t * DI + d];
        float b  = xdbl[t * 48 + RNK + n];
        float ct = xdbl[t * 48 + RNK + NST + n];
        h = expf(Adn * dl) * h + dl * b * u;
        float p = h * ct;
        p += __shfl_xor(p, 1);
        p += __shfl_xor(p, 2);
        p += __shfl_xor(p, 4);
        p += __shfl_xor(p, 8);
        if (n == 0) y[(size_t)t * (2 * DI) + d] = p;
    }
}

// ---------------- gate: g = (y + xc*D) * silu(res) -> bf16 hi/lo planes directly
__global__ __launch_bounds__(256) void gate_kernel(const float* __restrict__ xz,
                                                   const float* __restrict__ xc,
                                                   const float* __restrict__ Dp,
                                                   unsigned short* __restrict__ gh,
                                                   unsigned short* __restrict__ gl) {
    int idx = blockIdx.x * 256 + threadIdx.x;   // l*(DI/4) + d4
    int l = idx >> 9;
    int d = (idx & 511) << 2;
    float4 yv = *(const float4*)(xz + (size_t)l * (2 * DI) + d);
    float4 rv = *(const float4*)(xz + (size_t)l * (2 * DI) + DI + d);
    float4 xv = *(const float4*)(xc + (size_t)l * DI + d);
    float4 dv = *(const float4*)(Dp + d);
    float4 o;
    o.x = (yv.x + xv.x * dv.x) * (rv.x / (1.f + expf(-rv.x)));
    o.y = (yv.y + xv.y * dv.y) * (rv.y / (1.f + expf(-rv.y)));
    o.z = (yv.z + xv.z * dv.z) * (rv.z / (1.f + expf(-rv.z)));
    o.w = (yv.w + xv.w * dv.w) * (rv.w / (1.f + expf(-rv.w)));
    unsigned short hx = bfh(o.x), hy = bfh(o.y), hz = bfh(o.z), hw = bfh(o.w);
    u16x4 hv = {hx, hy, hz, hw};
    u16x4 lv = {bfh(o.x - bf2f(hx)), bfh(o.y - bf2f(hy)),
                bfh(o.z - bf2f(hz)), bfh(o.w - bf2f(hw))};
    *(u16x4*)(gh + (size_t)l * DI + d) = hv;
    *(u16x4*)(gl + (size_t)l * DI + d) = lv;
}

// ---------------- out_proj split-K reduce
__global__ __launch_bounds__(256) void out_reduce(const float* __restrict__ part,
                                                  float* __restrict__ out) {
    int i = blockIdx.x * 256 + threadIdx.x;
    float4 a = ((const float4*)part)[i];
    float4 b = ((const float4*)(part + (size_t)L * DM))[i];
    float4 o = {a.x + b.x, a.y + b.y, a.z + b.z, a.w + b.w};
    ((float4*)out)[i] = o;
}

extern "C" void kernel_launch(void* const* d_in, const int* in_sizes, int n_in,
                              void* d_out, int out_size, void* d_ws, size_t ws_size,
                              hipStream_t stream) {
    const float* x      = (const float*)d_in[0];
    const float* W_in   = (const float*)d_in[1];
    const float* conv_w = (const float*)d_in[2];
    const float* conv_b = (const float*)d_in[3];
    const float* W_x    = (const float*)d_in[4];
    const float* W_dt   = (const float*)d_in[5];
    const float* b_dt   = (const float*)d_in[6];
    const float* A_log  = (const float*)d_in[7];
    const float* Dp     = (const float*)d_in[8];
    const float* W_out  = (const float*)d_in[9];
    float* out = (float*)d_out;

    float* ws = (float*)d_ws;
    // fp32 regions (identical footprint to round 3 — lifetimes annotated)
    const size_t XZ_OFF    = 0;                                // xz (s1-s8); out partials (s9)
    const size_t XC_OFF    = XZ_OFF + (size_t)L * 2 * DI;      // Win planes (s0-s1); xc fp32 (s2-s8)
    const size_t DELTA_OFF = XC_OFF + (size_t)L * DI;          // x planes (s0-s1); xc planes (s2-s3); delta (s4-s7); g planes (s8-s9)
    const size_t XDBL_OFF  = DELTA_OFF + (size_t)L * DI;
    const size_t HLOC_OFF  = XDBL_OFF + 131072;                // xdbl part (s3); hloc (s5-s6); Wout planes (s8.5-s9)
    const size_t AEXP_OFF  = HLOC_OFF + (size_t)CCH * DI * NST;
    const size_t HINIT_OFF = AEXP_OFF + (size_t)CCH * DI * NST; // Wx planes (s2.5-s3); hinit (s6-s7)

    float* xz    = ws + XZ_OFF;
    float* xc    = ws + XC_OFF;
    float* delta = ws + DELTA_OFF;
    float* xdbl  = ws + XDBL_OFF;
    float* hloc  = ws + HLOC_OFF;
    float* aexp  = ws + AEXP_OFF;
    float* hinit = ws + HINIT_OFF;
    float* part  = hloc;                 // xdbl partials (1.57M fl <= 2.1M)
    float* y     = xz;                   // scan output into xz[:, :DI]
    float* opart = xz;                   // out_proj split-K partials (4.19M fl <= 8.39M)

    // bf16 plane aliases (each pair fits exactly in its host region)
    unsigned short* xh    = (unsigned short*)(ws + DELTA_OFF);
    unsigned short* xl    = xh + (size_t)L * DM;
    unsigned short* Winh  = (unsigned short*)(ws + XC_OFF);
    unsigned short* Winl  = Winh + (size_t)2 * DI * DM;
    unsigned short* xch   = (unsigned short*)(ws + DELTA_OFF);
    unsigned short* xcl   = xch + (size_t)L * DI;
    unsigned short* Wxh   = (unsigned short*)(ws + HINIT_OFF);
    unsigned short* Wxl   = Wxh + (size_t)48 * DI;
    unsigned short* gh    = (unsigned short*)(ws + DELTA_OFF);
    unsigned short* gl    = gh + (size_t)L * DI;
    unsigned short* Wouth = (unsigned short*)(ws + HLOC_OFF);
    unsigned short* Woutl = Wouth + (size_t)DM * DI;

    // 0. pre-split x, W_in, W_x
    split_kernel<<<(L * DM / 4) / 256, 256, 0, stream>>>(x, xh, xl);
    split_kernel<<<(2 * DI * DM / 4) / 256, 256, 0, stream>>>(W_in, Winh, Winl);
    split_kernel<<<(48 * DI / 4) / 256, 256, 0, stream>>>(W_x, Wxh, Wxl);

    // 1. in_proj: xz[L, 2*DI] = x @ W_in^T
    gemm_pl<128, 128><<<dim3(L / 128, (2 * DI) / 128, 1), 256, 0, stream>>>(
        xh, xl, Winh, Winl, xz, L, 2 * DI, DM, DM);

    // 2. conv + silu -> xc fp32 + planes
    conv_silu_kernel<<<(L * DI / 4) / 256, 256, 0, stream>>>(xz, conv_w, conv_b, xc, xch, xcl);

    // 3. x_dbl: split-K MFMA + reduce
    xdbl_mfma<<<dim3(L / 128, XKC), 256, 0, stream>>>(xch, xcl, Wxh, Wxl, part);
    xdbl_reduce<<<(L * 48) / 256, 256, 0, stream>>>(part, xdbl);

    // 4. delta
    delta_kernel<<<(L * DI) / 256, 256, 0, stream>>>(xdbl, W_dt, b_dt, delta);

    // 5-7. selective scan
    scan_a<<<(CCH * DI * NST) / 256, 256, 0, stream>>>(delta, xc, xdbl, A_log, hloc, aexp);
    scan_b<<<(DI * NST) / 256, 256, 0, stream>>>(hloc, aexp, hinit);
    scan_c<<<(CCH * DI * NST) / 256, 256, 0, stream>>>(delta, xc, xdbl, A_log, hinit, y);

    // 8. gate -> g planes (delta region; delta is dead)
    gate_kernel<<<(L * DI / 4) / 256, 256, 0, stream>>>(xz, xc, Dp, gh, gl);

    // 8.5. split W_out into hloc/aexp region (dead after scan_b)
    split_kernel<<<(DM * DI / 4) / 256, 256, 0, stream>>>(W_out, Wouth, Woutl);

    // 9. out_proj split-K x2 -> partials in xz region (dead after gate)
    gemm_pl<64, 128><<<dim3(L / 64, DM / 128, 2), 256, 0, stream>>>(
        gh, gl, Wouth, Woutl, opart, L, DM, DI, DI / 2);
    out_reduce<<<(L * DM / 4) / 256, 256, 0, stream>>>(opart, out);
}

// Round 5
// 232.155 us; speedup vs baseline: 3.4653x; 1.3274x over previous
//
#include <hip/hip_runtime.h>
#include <hip/hip_bf16.h>
#include <math.h>

// Problem dims (compile-time)
#define L     2048
#define DM    1024
#define DI    2048
#define DCONV 4
#define RNK   16
#define NST   16
#define CCH   64          // number of scan chunks
#define TCH   (L / CCH)   // steps per chunk = 32

#define XKC   16          // xdbl split-K chunks
#define XKK   (DI / XKC)  // 128 = 4 k-steps of 32

typedef __attribute__((ext_vector_type(8))) short bf16x8;   // 8 bf16 in 4 VGPRs
typedef __attribute__((ext_vector_type(4))) float f32x4;
typedef __attribute__((ext_vector_type(4))) unsigned short u16x4;
typedef __attribute__((ext_vector_type(8))) unsigned short u16x8;

// ---- fp32 -> bf16 (RNE) split helpers ----
__device__ __forceinline__ unsigned short bfh(float f) {
    unsigned u = __float_as_uint(f);
    unsigned r = u + 0x7FFFu + ((u >> 16) & 1u);
    return (unsigned short)(r >> 16);
}
__device__ __forceinline__ float bf2f(unsigned short h) {
    return __uint_as_float(((unsigned)h) << 16);
}

// Swizzled LDS byte offset for a [R][32]-bf16 tile (row = 64 B).
// Verified conflict-free: SQ_LDS_BANK_CONFLICT == 0 (rounds 3-4).
__device__ __forceinline__ int swz_byte(int row, int q) {
    return row * 64 + ((q ^ ((row >> 1) & 3)) << 4);
}

__device__ __forceinline__ bf16x8 rdfrag(const unsigned short* base, int row, int q) {
    return *(const bf16x8*)((const char*)base + swz_byte(row, q));
}

// ---------------- split fp32 array into bf16 hi/lo planes (once per buffer)
__global__ __launch_bounds__(256) void split_kernel(const float* __restrict__ in,
                                                    unsigned short* __restrict__ h,
                                                    unsigned short* __restrict__ l) {
    int i = blockIdx.x * 256 + threadIdx.x;
    float4 v = ((const float4*)in)[i];
    unsigned short hx = bfh(v.x), hy = bfh(v.y), hz = bfh(v.z), hw = bfh(v.w);
    u16x4 hv = {hx, hy, hz, hw};
    u16x4 lv = {bfh(v.x - bf2f(hx)), bfh(v.y - bf2f(hy)),
                bfh(v.z - bf2f(hz)), bfh(v.w - bf2f(hw))};
    ((u16x4*)h)[i] = hv;
    ((u16x4*)l)[i] = lv;
}

// Simple (non-pipelined) plane staging for the small xdbl GEMM.
template<int R>
__device__ __forceinline__ void stage_pl(const unsigned short* __restrict__ gh,
                                         const unsigned short* __restrict__ gl,
                                         int ldK, int k0,
                                         unsigned short* sh, unsigned short* sl, int tid) {
#pragma unroll
    for (int c0 = 0; c0 < R * 4; c0 += 256) {
        int c = c0 + tid;
        if ((R * 4 % 256 == 0) || c < R * 4) {
            int row = c >> 2, q = c & 3;
            size_t off = (size_t)row * ldK + k0 + q * 8;
            u16x8 hv = *(const u16x8*)(gh + off);
            u16x8 lv = *(const u16x8*)(gl + off);
            int byte = swz_byte(row, q);
            *(u16x8*)((char*)sh + byte) = hv;
            *(u16x8*)((char*)sl + byte) = lv;
        }
    }
}

// C[M,N] (+z*M*N) = A[M, kStart:kStart+kLen] * B[N, ...]^T, planes pre-split.
// T14 pipeline: ds_write tile k, then issue global loads for k+1, then MFMA.
template<int BM, int BN>
__global__ __launch_bounds__(256) void gemm_pl(const unsigned short* __restrict__ Agh,
                                               const unsigned short* __restrict__ Agl,
                                               const unsigned short* __restrict__ Bgh,
                                               const unsigned short* __restrict__ Bgl,
                                               float* __restrict__ C,
                                               int M, int N, int K, int kLen) {
    __shared__ __align__(16) unsigned short Ah[BM * 32];
    __shared__ __align__(16) unsigned short Al[BM * 32];
    __shared__ __align__(16) unsigned short Bh[BN * 32];
    __shared__ __align__(16) unsigned short Bl[BN * 32];

    const int tid = threadIdx.x;
    const int bm = blockIdx.x * BM, bn = blockIdx.y * BN;
    const int kStart = blockIdx.z * kLen;
    const int l = tid & 63, wv = tid >> 6;
    const int wr = (wv >> 1) * (BM / 2), wc = (wv & 1) * (BN / 2);
    constexpr int MR = BM / 32, NR = BN / 32;
    const int fr = l & 15, q = l >> 4;

    constexpr int CA = (BM * 4) / 256;   // 16B chunks per thread, per A plane
    constexpr int CB = (BN * 4) / 256;

    u16x8 rAh[CA], rAl[CA], rBh[CB], rBl[CB];

    f32x4 acc[MR][NR];
#pragma unroll
    for (int m = 0; m < MR; ++m)
#pragma unroll
        for (int n = 0; n < NR; ++n) acc[m][n] = (f32x4){0.f, 0.f, 0.f, 0.f};

    // prologue: load tile 0
#pragma unroll
    for (int c = 0; c < CA; ++c) {
        int cc = c * 256 + tid, row = cc >> 2, qq = cc & 3;
        size_t off = (size_t)(bm + row) * K + kStart + qq * 8;
        rAh[c] = *(const u16x8*)(Agh + off);
        rAl[c] = *(const u16x8*)(Agl + off);
    }
#pragma unroll
    for (int c = 0; c < CB; ++c) {
        int cc = c * 256 + tid, row = cc >> 2, qq = cc & 3;
        size_t off = (size_t)(bn + row) * K + kStart + qq * 8;
        rBh[c] = *(const u16x8*)(Bgh + off);
        rBl[c] = *(const u16x8*)(Bgl + off);
    }

    for (int ks = 0; ks < kLen; ks += 32) {
        // write staged regs to LDS (waits vmcnt on the loads issued last iter)
#pragma unroll
        for (int c = 0; c < CA; ++c) {
            int cc = c * 256 + tid, row = cc >> 2, qq = cc & 3;
            int byte = swz_byte(row, qq);
            *(u16x8*)((char*)Ah + byte) = rAh[c];
            *(u16x8*)((char*)Al + byte) = rAl[c];
        }
#pragma unroll
        for (int c = 0; c < CB; ++c) {
            int cc = c * 256 + tid, row = cc >> 2, qq = cc & 3;
            int byte = swz_byte(row, qq);
            *(u16x8*)((char*)Bh + byte) = rBh[c];
            *(u16x8*)((char*)Bl + byte) = rBl[c];
        }
        // issue next tile's loads; they complete under the MFMA phase
        if (ks + 32 < kLen) {
            int k1 = kStart + ks + 32;
#pragma unroll
            for (int c = 0; c < CA; ++c) {
                int cc = c * 256 + tid, row = cc >> 2, qq = cc & 3;
                size_t off = (size_t)(bm + row) * K + k1 + qq * 8;
                rAh[c] = *(const u16x8*)(Agh + off);
                rAl[c] = *(const u16x8*)(Agl + off);
            }
#pragma unroll
            for (int c = 0; c < CB; ++c) {
                int cc = c * 256 + tid, row = cc >> 2, qq = cc & 3;
                size_t off = (size_t)(bn + row) * K + k1 + qq * 8;
                rBh[c] = *(const u16x8*)(Bgh + off);
                rBl[c] = *(const u16x8*)(Bgl + off);
            }
        }
        __syncthreads();

        bf16x8 ah[MR], av[MR], bh[NR], bv[NR];
#pragma unroll
        for (int m = 0; m < MR; ++m) {
            int row = wr + m * 16 + fr;
            ah[m] = rdfrag(Ah, row, q);
            av[m] = rdfrag(Al, row, q);
        }
#pragma unroll
        for (int n = 0; n < NR; ++n) {
            int row = wc + n * 16 + fr;
            bh[n] = rdfrag(Bh, row, q);
            bv[n] = rdfrag(Bl, row, q);
        }
#pragma unroll
        for (int m = 0; m < MR; ++m)
#pragma unroll
            for (int n = 0; n < NR; ++n) {
                acc[m][n] = __builtin_amdgcn_mfma_f32_16x16x32_bf16(av[m], bh[n], acc[m][n], 0, 0, 0);
                acc[m][n] = __builtin_amdgcn_mfma_f32_16x16x32_bf16(ah[m], bv[n], acc[m][n], 0, 0, 0);
                acc[m][n] = __builtin_amdgcn_mfma_f32_16x16x32_bf16(ah[m], bh[n], acc[m][n], 0, 0, 0);
            }
        __syncthreads();
    }

    float* Cz = C + (size_t)blockIdx.z * M * N;
#pragma unroll
    for (int m = 0; m < MR; ++m)
#pragma unroll
        for (int n = 0; n < NR; ++n) {
            int row0 = bm + wr + m * 16 + q * 4;
            int col  = bn + wc + n * 16 + fr;
#pragma unroll
            for (int r = 0; r < 4; ++r)
                Cz[(size_t)(row0 + r) * N + col] = acc[m][n][r];
        }
}

// ---------------- xdbl split-K MFMA from planes
__global__ __launch_bounds__(256) void xdbl_mfma(const unsigned short* __restrict__ xch,
                                                 const unsigned short* __restrict__ xcl,
                                                 const unsigned short* __restrict__ Wxh,
                                                 const unsigned short* __restrict__ Wxl,
                                                 float* __restrict__ part) {
    __shared__ __align__(16) unsigned short Ah[128 * 32];
    __shared__ __align__(16) unsigned short Al[128 * 32];
    __shared__ __align__(16) unsigned short Bh[48 * 32];
    __shared__ __align__(16) unsigned short Bl[48 * 32];

    const int tid = threadIdx.x;
    const int bm = blockIdx.x * 128;
    const int kc = blockIdx.y;
    const int l = tid & 63, wv = tid >> 6;
    const int wr = wv * 32;
    const int fr = l & 15, q = l >> 4;

    f32x4 acc[2][3];
#pragma unroll
    for (int m = 0; m < 2; ++m)
#pragma unroll
        for (int n = 0; n < 3; ++n) acc[m][n] = (f32x4){0.f, 0.f, 0.f, 0.f};

    for (int ks = 0; ks < XKK; ks += 32) {
        int k0 = kc * XKK + ks;
        stage_pl<128>(xch + (size_t)bm * DI, xcl + (size_t)bm * DI, DI, k0, Ah, Al, tid);
        stage_pl<48>(Wxh, Wxl, DI, k0, Bh, Bl, tid);
        __syncthreads();

        bf16x8 ah[2], av[2], bh[3], bv[3];
#pragma unroll
        for (int m = 0; m < 2; ++m) {
            int row = wr + m * 16 + fr;
            ah[m] = rdfrag(Ah, row, q);
            av[m] = rdfrag(Al, row, q);
        }
#pragma unroll
        for (int n = 0; n < 3; ++n) {
            int row = n * 16 + fr;
            bh[n] = rdfrag(Bh, row, q);
            bv[n] = rdfrag(Bl, row, q);
        }
#pragma unroll
        for (int m = 0; m < 2; ++m)
#pragma unroll
            for (int n = 0; n < 3; ++n) {
                acc[m][n] = __builtin_amdgcn_mfma_f32_16x16x32_bf16(av[m], bh[n], acc[m][n], 0, 0, 0);
                acc[m][n] = __builtin_amdgcn_mfma_f32_16x16x32_bf16(ah[m], bv[n], acc[m][n], 0, 0, 0);
                acc[m][n] = __builtin_amdgcn_mfma_f32_16x16x32_bf16(ah[m], bh[n], acc[m][n], 0, 0, 0);
            }
        __syncthreads();
    }

#pragma unroll
    for (int m = 0; m < 2; ++m)
#pragma unroll
        for (int n = 0; n < 3; ++n) {
            int row0 = bm + wr + m * 16 + q * 4;
            int col  = n * 16 + fr;
#pragma unroll
            for (int r = 0; r < 4; ++r)
                part[(size_t)kc * (L * 48) + (size_t)(row0 + r) * 48 + col] = acc[m][n][r];
        }
}

__global__ __launch_bounds__(256) void xdbl_reduce(const float* __restrict__ part,
                                                   float* __restrict__ xdbl) {
    int i = blockIdx.x * 256 + threadIdx.x;
    float s = 0.f;
#pragma unroll
    for (int kc = 0; kc < XKC; ++kc) s += part[(size_t)kc * (L * 48) + i];
    xdbl[i] = s;
}

// ---------------- depthwise causal conv (k=4) + silu; writes fp32 xc + bf16 planes
__global__ __launch_bounds__(256) void conv_silu_kernel(const float* __restrict__ xz,
                                                        const float* __restrict__ cw,
                                                        const float* __restrict__ cb,
                                                        float* __restrict__ xc,
                                                        unsigned short* __restrict__ xch,
                                                        unsigned short* __restrict__ xcl) {
    int idx = blockIdx.x * 256 + threadIdx.x;   // l*(DI/4) + d4
    int l = idx >> 9;
    int d = (idx & 511) << 2;
    float4 s = *(const float4*)(cb + d);
    float4 w0 = *(const float4*)(cw + (d + 0) * 4);
    float4 w1 = *(const float4*)(cw + (d + 1) * 4);
    float4 w2 = *(const float4*)(cw + (d + 2) * 4);
    float4 w3 = *(const float4*)(cw + (d + 3) * 4);
#pragma unroll
    for (int k = 0; k < DCONV; ++k) {
        int t = l - (DCONV - 1) + k;
        if (t >= 0) {
            float4 xv = *(const float4*)(xz + (size_t)t * (2 * DI) + d);
            s.x += ((const float*)&w0)[k] * xv.x;
            s.y += ((const float*)&w1)[k] * xv.y;
            s.z += ((const float*)&w2)[k] * xv.z;
            s.w += ((const float*)&w3)[k] * xv.w;
        }
    }
    float4 o;
    o.x = s.x / (1.f + expf(-s.x));
    o.y = s.y / (1.f + expf(-s.y));
    o.z = s.z / (1.f + expf(-s.z));
    o.w = s.w / (1.f + expf(-s.w));
    *(float4*)(xc + (size_t)l * DI + d) = o;
    unsigned short hx = bfh(o.x), hy = bfh(o.y), hz = bfh(o.z), hw = bfh(o.w);
    u16x4 hv = {hx, hy, hz, hw};
    u16x4 lv = {bfh(o.x - bf2f(hx)), bfh(o.y - bf2f(hy)),
                bfh(o.z - bf2f(hz)), bfh(o.w - bf2f(hw))};
    *(u16x4*)(xch + (size_t)l * DI + d) = hv;
    *(u16x4*)(xcl + (size_t)l * DI + d) = lv;
}

// ---------------- delta[l,d] = softplus(xdbl[l,:16] @ W_dt[d,:] + b_dt[d])
__global__ __launch_bounds__(256) void delta_kernel(const float* __restrict__ xdbl,
                                                    const float* __restrict__ Wdt,
                                                    const float* __restrict__ bdt,
                                                    float* __restrict__ delta) {
    int idx = blockIdx.x * 256 + threadIdx.x;
    int l = idx >> 11;
    int d = idx & (DI - 1);
    float s = bdt[d];
    const float4* xr = (const float4*)(xdbl + l * 48);
    const float4* wr = (const float4*)(Wdt + d * RNK);
#pragma unroll
    for (int c = 0; c < 4; ++c) {
        float4 xv = xr[c], wv = wr[c];
        s += xv.x * wv.x + xv.y * wv.y + xv.z * wv.z + xv.w * wv.w;
    }
    delta[idx] = fmaxf(s, 0.f) + log1pf(expf(-fabsf(s)));   // jax softplus
}

// ---------------- scan phase A: register-resident n (no shuffles)
// thread = (chunk c, channel d); h[16], Adn[16] in regs; B row broadcast from LDS
__global__ __launch_bounds__(256) void scan_a(const float* __restrict__ delta,
                                              const float* __restrict__ xc,
                                              const float* __restrict__ xdbl,
                                              const float* __restrict__ A_log,
                                              float* __restrict__ hloc,
                                              float* __restrict__ dsum) {
    __shared__ float sb[TCH][16];
    const int tid = threadIdx.x;
    const int c = blockIdx.x >> 3;                 // DI/256 = 8 blocks per chunk
    const int d = ((blockIdx.x & 7) << 8) + tid;
    const int t0 = c * TCH;
    for (int i = tid; i < TCH * 16; i += 256) {
        int tt = i >> 4, n = i & 15;
        sb[tt][n] = xdbl[(t0 + tt) * 48 + RNK + n];
    }
    __syncthreads();

    float Adn[16], h[16];
#pragma unroll
    for (int n = 0; n < 16; ++n) {
        Adn[n] = -expf(A_log[d * 16 + n]);
        h[n] = 0.f;
    }
    float ds = 0.f;
    for (int t = t0; t < t0 + TCH; ++t) {
        float dl = delta[(size_t)t * DI + d];
        float u  = xc[(size_t)t * DI + d];
        float du = dl * u;
        ds += dl;
        const float4* b4 = (const float4*)sb[t - t0];
#pragma unroll
        for (int j = 0; j < 4; ++j) {
            float4 b = b4[j];
            h[4*j+0] = __expf(Adn[4*j+0] * dl) * h[4*j+0] + du * b.x;
            h[4*j+1] = __expf(Adn[4*j+1] * dl) * h[4*j+1] + du * b.y;
            h[4*j+2] = __expf(Adn[4*j+2] * dl) * h[4*j+2] + du * b.z;
            h[4*j+3] = __expf(Adn[4*j+3] * dl) * h[4*j+3] + du * b.w;
        }
    }
    size_t base = ((size_t)c * DI + d) * 16;
#pragma unroll
    for (int j = 0; j < 4; ++j) {
        float4 o = {h[4*j+0], h[4*j+1], h[4*j+2], h[4*j+3]};
        *(float4*)(hloc + base + 4*j) = o;
    }
    dsum[c * DI + d] = ds;
}

// ---------------- scan phase B: inter-chunk combine; hinit written in place
__global__ __launch_bounds__(256) void scan_b(float* __restrict__ hloc,
                                              const float* __restrict__ dsum,
                                              const float* __restrict__ A_log) {
    int i = blockIdx.x * 256 + threadIdx.x;   // d*16+n  (== A_log flat index)
    float Adn = -expf(A_log[i]);
    float h = 0.f;
    for (int c = 0; c < CCH; ++c) {
        size_t off = (size_t)c * (DI * NST) + i;
        float hl = hloc[off];
        hloc[off] = h;                         // becomes hinit
        h = __expf(Adn * dsum[c * DI + (i >> 4)]) * h + hl;
    }
}

// ---------------- scan phase C: replay with correct init; in-register C-dot
__global__ __launch_bounds__(256) void scan_c(const float* __restrict__ delta,
                                              const float* __restrict__ xc,
                                              const float* __restrict__ xdbl,
                                              const float* __restrict__ A_log,
                                              const float* __restrict__ hinit,
                                              float* __restrict__ y /* stride 2*DI */) {
    __shared__ float sb[TCH][16];
    __shared__ float sc[TCH][16];
    const int tid = threadIdx.x;
    const int c = blockIdx.x >> 3;
    const int d = ((blockIdx.x & 7) << 8) + tid;
    const int t0 = c * TCH;
    for (int i = tid; i < TCH * 16; i += 256) {
        int tt = i >> 4, n = i & 15;
        sb[tt][n] = xdbl[(t0 + tt) * 48 + RNK + n];
        sc[tt][n] = xdbl[(t0 + tt) * 48 + RNK + NST + n];
    }
    __syncthreads();

    float Adn[16], h[16];
    size_t base = ((size_t)c * DI + d) * 16;
#pragma unroll
    for (int j = 0; j < 4; ++j) {
        float4 hv = *(const float4*)(hinit + base + 4*j);
        h[4*j+0] = hv.x; h[4*j+1] = hv.y; h[4*j+2] = hv.z; h[4*j+3] = hv.w;
    }
#pragma unroll
    for (int n = 0; n < 16; ++n) Adn[n] = -expf(A_log[d * 16 + n]);

    for (int t = t0; t < t0 + TCH; ++t) {
        float dl = delta[(size_t)t * DI + d];
        float u  = xc[(size_t)t * DI + d];
        float du = dl * u;
        const float4* b4 = (const float4*)sb[t - t0];
        const float4* c4 = (const float4*)sc[t - t0];
        float acc = 0.f;
#pragma unroll
        for (int j = 0; j < 4; ++j) {
            float4 b = b4[j];
            float4 ct = c4[j];
            h[4*j+0] = __expf(Adn[4*j+0] * dl) * h[4*j+0] + du * b.x;
            h[4*j+1] = __expf(Adn[4*j+1] * dl) * h[4*j+1] + du * b.y;
            h[4*j+2] = __expf(Adn[4*j+2] * dl) * h[4*j+2] + du * b.z;
            h[4*j+3] = __expf(Adn[4*j+3] * dl) * h[4*j+3] + du * b.w;
            acc += h[4*j+0] * ct.x + h[4*j+1] * ct.y + h[4*j+2] * ct.z + h[4*j+3] * ct.w;
        }
        y[(size_t)t * (2 * DI) + d] = acc;
    }
}

// ---------------- gate: g = (y + xc*D) * silu(res) -> bf16 hi/lo planes directly
__global__ __launch_bounds__(256) void gate_kernel(const float* __restrict__ xz,
                                                   const float* __restrict__ xc,
                                                   const float* __restrict__ Dp,
                                                   unsigned short* __restrict__ gh,
                                                   unsigned short* __restrict__ gl) {
    int idx = blockIdx.x * 256 + threadIdx.x;   // l*(DI/4) + d4
    int l = idx >> 9;
    int d = (idx & 511) << 2;
    float4 yv = *(const float4*)(xz + (size_t)l * (2 * DI) + d);
    float4 rv = *(const float4*)(xz + (size_t)l * (2 * DI) + DI + d);
    float4 xv = *(const float4*)(xc + (size_t)l * DI + d);
    float4 dv = *(const float4*)(Dp + d);
    float4 o;
    o.x = (yv.x + xv.x * dv.x) * (rv.x / (1.f + expf(-rv.x)));
    o.y = (yv.y + xv.y * dv.y) * (rv.y / (1.f + expf(-rv.y)));
    o.z = (yv.z + xv.z * dv.z) * (rv.z / (1.f + expf(-rv.z)));
    o.w = (yv.w + xv.w * dv.w) * (rv.w / (1.f + expf(-rv.w)));
    unsigned short hx = bfh(o.x), hy = bfh(o.y), hz = bfh(o.z), hw = bfh(o.w);
    u16x4 hv = {hx, hy, hz, hw};
    u16x4 lv = {bfh(o.x - bf2f(hx)), bfh(o.y - bf2f(hy)),
                bfh(o.z - bf2f(hz)), bfh(o.w - bf2f(hw))};
    *(u16x4*)(gh + (size_t)l * DI + d) = hv;
    *(u16x4*)(gl + (size_t)l * DI + d) = lv;
}

// ---------------- out_proj split-K reduce
__global__ __launch_bounds__(256) void out_reduce(const float* __restrict__ part,
                                                  float* __restrict__ out) {
    int i = blockIdx.x * 256 + threadIdx.x;
    float4 a = ((const float4*)part)[i];
    float4 b = ((const float4*)(part + (size_t)L * DM))[i];
    float4 o = {a.x + b.x, a.y + b.y, a.z + b.z, a.w + b.w};
    ((float4*)out)[i] = o;
}

extern "C" void kernel_launch(void* const* d_in, const int* in_sizes, int n_in,
                              void* d_out, int out_size, void* d_ws, size_t ws_size,
                              hipStream_t stream) {
    const float* x      = (const float*)d_in[0];
    const float* W_in   = (const float*)d_in[1];
    const float* conv_w = (const float*)d_in[2];
    const float* conv_b = (const float*)d_in[3];
    const float* W_x    = (const float*)d_in[4];
    const float* W_dt   = (const float*)d_in[5];
    const float* b_dt   = (const float*)d_in[6];
    const float* A_log  = (const float*)d_in[7];
    const float* Dp     = (const float*)d_in[8];
    const float* W_out  = (const float*)d_in[9];
    float* out = (float*)d_out;

    float* ws = (float*)d_ws;
    // fp32 regions (total 19.1M floats = 76.5 MB, < round-4's 80.2 MB)
    const size_t XZ_OFF    = 0;                                // xz (s1-s8); out partials (s9)
    const size_t XC_OFF    = XZ_OFF + (size_t)L * 2 * DI;      // Win planes (s0-s1); xc fp32 (s2-s8)
    const size_t DELTA_OFF = XC_OFF + (size_t)L * DI;          // x planes (s0-s1); xc planes (s2-s3); delta (s4-s7); g planes (s8-s9)
    const size_t XDBL_OFF  = DELTA_OFF + (size_t)L * DI;       // xdbl
    const size_t HLOC_OFF  = XDBL_OFF + 131072;                // xdbl part (s3); hloc/hinit (s5-s7); Wout planes (s8.5-s9)
    const size_t DSUM_OFF  = HLOC_OFF + (size_t)CCH * DI * NST; // Wx planes (s0-s3); dsum (s5-s6)

    float* xz    = ws + XZ_OFF;
    float* xc    = ws + XC_OFF;
    float* delta = ws + DELTA_OFF;
    float* xdbl  = ws + XDBL_OFF;
    float* hloc  = ws + HLOC_OFF;
    float* dsum  = ws + DSUM_OFF;
    float* part  = hloc;                 // xdbl partials (1.57M fl <= 2.1M)
    float* y     = xz;                   // scan output into xz[:, :DI]
    float* opart = xz;                   // out_proj split-K partials (4.19M <= 8.39M)

    // bf16 plane aliases
    unsigned short* xh    = (unsigned short*)(ws + DELTA_OFF);
    unsigned short* xl    = xh + (size_t)L * DM;
    unsigned short* Winh  = (unsigned short*)(ws + XC_OFF);
    unsigned short* Winl  = Winh + (size_t)2 * DI * DM;
    unsigned short* xch   = (unsigned short*)(ws + DELTA_OFF);
    unsigned short* xcl   = xch + (size_t)L * DI;
    unsigned short* Wxh   = (unsigned short*)(ws + DSUM_OFF);   // 196K u16 <= 131K floats
    unsigned short* Wxl   = Wxh + (size_t)48 * DI;
    unsigned short* gh    = (unsigned short*)(ws + DELTA_OFF);
    unsigned short* gl    = gh + (size_t)L * DI;
    unsigned short* Wouth = (unsigned short*)(ws + HLOC_OFF);   // 4.19M u16 == 2.1M floats
    unsigned short* Woutl = Wouth + (size_t)DM * DI;

    // 0. pre-split x, W_in, W_x
    split_kernel<<<(L * DM / 4) / 256, 256, 0, stream>>>(x, xh, xl);
    split_kernel<<<(2 * DI * DM / 4) / 256, 256, 0, stream>>>(W_in, Winh, Winl);
    split_kernel<<<(48 * DI / 4) / 256, 256, 0, stream>>>(W_x, Wxh, Wxl);

    // 1. in_proj: xz[L, 2*DI] = x @ W_in^T
    gemm_pl<128, 128><<<dim3(L / 128, (2 * DI) / 128, 1), 256, 0, stream>>>(
        xh, xl, Winh, Winl, xz, L, 2 * DI, DM, DM);

    // 2. conv + silu -> xc fp32 + planes
    conv_silu_kernel<<<(L * DI / 4) / 256, 256, 0, stream>>>(xz, conv_w, conv_b, xc, xch, xcl);

    // 3. x_dbl: split-K MFMA + reduce
    xdbl_mfma<<<dim3(L / 128, XKC), 256, 0, stream>>>(xch, xcl, Wxh, Wxl, part);
    xdbl_reduce<<<(L * 48) / 256, 256, 0, stream>>>(part, xdbl);

    // 4. delta
    delta_kernel<<<(L * DI) / 256, 256, 0, stream>>>(xdbl, W_dt, b_dt, delta);

    // 5-7. selective scan (register-n formulation)
    scan_a<<<CCH * (DI / 256), 256, 0, stream>>>(delta, xc, xdbl, A_log, hloc, dsum);
    scan_b<<<(DI * NST) / 256, 256, 0, stream>>>(hloc, dsum, A_log);
    scan_c<<<CCH * (DI / 256), 256, 0, stream>>>(delta, xc, xdbl, A_log, hloc, y);

    // 8. gate -> g planes (delta region; delta is dead)
    gate_kernel<<<(L * DI / 4) / 256, 256, 0, stream>>>(xz, xc, Dp, gh, gl);

    // 8.5. split W_out into hloc region (dead after scan_c)
    split_kernel<<<(DM * DI / 4) / 256, 256, 0, stream>>>(W_out, Wouth, Woutl);

    // 9. out_proj split-K x2 -> partials in xz region (dead after gate)
    gemm_pl<64, 128><<<dim3(L / 64, DM / 128, 2), 256, 0, stream>>>(
        gh, gl, Wouth, Woutl, opart, L, DM, DI, DI / 2);
    out_reduce<<<(L * DM / 4) / 256, 256, 0, stream>>>(opart, out);
}

// Round 6
// 224.804 us; speedup vs baseline: 3.5787x; 1.0327x over previous
//
#include <hip/hip_runtime.h>
#include <hip/hip_bf16.h>
#include <math.h>

// Problem dims (compile-time)
#define L     2048
#define DM    1024
#define DI    2048
#define DCONV 4
#define RNK   16
#define NST   16
#define CCH   64          // number of scan chunks
#define TCH   (L / CCH)   // steps per chunk = 32

#define XKC   16          // xdbl split-K chunks
#define XKK   (DI / XKC)  // 128 = 4 k-steps of 32

typedef __attribute__((ext_vector_type(8))) short bf16x8;   // 8 bf16 in 4 VGPRs
typedef __attribute__((ext_vector_type(4))) float f32x4;
typedef __attribute__((ext_vector_type(4))) unsigned short u16x4;
typedef __attribute__((ext_vector_type(8))) unsigned short u16x8;

// ---- fp32 -> bf16 (RNE) split helpers ----
__device__ __forceinline__ unsigned short bfh(float f) {
    unsigned u = __float_as_uint(f);
    unsigned r = u + 0x7FFFu + ((u >> 16) & 1u);
    return (unsigned short)(r >> 16);
}
__device__ __forceinline__ float bf2f(unsigned short h) {
    return __uint_as_float(((unsigned)h) << 16);
}
__device__ __forceinline__ void split4(float4 v, unsigned short* hp, unsigned short* lp, size_t i4) {
    unsigned short hx = bfh(v.x), hy = bfh(v.y), hz = bfh(v.z), hw = bfh(v.w);
    u16x4 hv = {hx, hy, hz, hw};
    u16x4 lv = {bfh(v.x - bf2f(hx)), bfh(v.y - bf2f(hy)),
                bfh(v.z - bf2f(hz)), bfh(v.w - bf2f(hw))};
    ((u16x4*)hp)[i4] = hv;
    ((u16x4*)lp)[i4] = lv;
}

// Swizzled LDS byte offset for a [R][32]-bf16 tile (row = 64 B).
// Verified conflict-free: SQ_LDS_BANK_CONFLICT == 0 (rounds 3-5).
__device__ __forceinline__ int swz_byte(int row, int q) {
    return row * 64 + ((q ^ ((row >> 1) & 3)) << 4);
}

__device__ __forceinline__ bf16x8 rdfrag(const unsigned short* base, int row, int q) {
    return *(const bf16x8*)((const char*)base + swz_byte(row, q));
}

// ---------------- fused pre-split of x, W_in, W_x (one launch)
#define XF4   (L * DM / 4)            // 524288
#define WINF4 (2 * DI * DM / 4)       // 1048576
#define WXF4  (48 * DI / 4)           // 24576
__global__ __launch_bounds__(256) void split3_kernel(const float* __restrict__ x,
                                                     const float* __restrict__ W_in,
                                                     const float* __restrict__ W_x,
                                                     unsigned short* __restrict__ xh,
                                                     unsigned short* __restrict__ xl,
                                                     unsigned short* __restrict__ Winh,
                                                     unsigned short* __restrict__ Winl,
                                                     unsigned short* __restrict__ Wxh,
                                                     unsigned short* __restrict__ Wxl) {
    int i = blockIdx.x * 256 + threadIdx.x;
    if (i < XF4) {
        split4(((const float4*)x)[i], xh, xl, i);
    } else if (i < XF4 + WINF4) {
        int j = i - XF4;
        split4(((const float4*)W_in)[j], Winh, Winl, j);
    } else {
        int j = i - XF4 - WINF4;
        if (j < WXF4) split4(((const float4*)W_x)[j], Wxh, Wxl, j);
    }
}

// Simple (non-pipelined) plane staging for the small xdbl GEMM.
template<int R>
__device__ __forceinline__ void stage_pl(const unsigned short* __restrict__ gh,
                                         const unsigned short* __restrict__ gl,
                                         int ldK, int k0,
                                         unsigned short* sh, unsigned short* sl, int tid) {
#pragma unroll
    for (int c0 = 0; c0 < R * 4; c0 += 256) {
        int c = c0 + tid;
        if ((R * 4 % 256 == 0) || c < R * 4) {
            int row = c >> 2, q = c & 3;
            size_t off = (size_t)row * ldK + k0 + q * 8;
            u16x8 hv = *(const u16x8*)(gh + off);
            u16x8 lv = *(const u16x8*)(gl + off);
            int byte = swz_byte(row, q);
            *(u16x8*)((char*)sh + byte) = hv;
            *(u16x8*)((char*)sl + byte) = lv;
        }
    }
}

// C[M,N] (+z*M*N) = A[M, kStart:kStart+kLen] * B[N, ...]^T, planes pre-split.
// T14 pipeline + bijective XCD block swizzle (grid size must be %8==0).
template<int BM, int BN>
__global__ __launch_bounds__(256) void gemm_pl(const unsigned short* __restrict__ Agh,
                                               const unsigned short* __restrict__ Agl,
                                               const unsigned short* __restrict__ Bgh,
                                               const unsigned short* __restrict__ Bgl,
                                               float* __restrict__ C,
                                               int M, int N, int K, int kLen) {
    __shared__ __align__(16) unsigned short Ah[BM * 32];
    __shared__ __align__(16) unsigned short Al[BM * 32];
    __shared__ __align__(16) unsigned short Bh[BN * 32];
    __shared__ __align__(16) unsigned short Bl[BN * 32];

    const int tid = threadIdx.x;

    // T1: bijective XCD swizzle of the flat workgroup id (nwg % 8 == 0)
    const int nbx = gridDim.x, nby = gridDim.y;
    const int nwg = nbx * nby * gridDim.z;
    int flat = blockIdx.x + nbx * (blockIdx.y + nby * blockIdx.z);
    int swz = (flat & 7) * (nwg >> 3) + (flat >> 3);
    const int bz = swz / (nbx * nby);
    int rem = swz % (nbx * nby);
    const int bm = (rem % nbx) * BM, bn = (rem / nbx) * BN;

    const int kStart = bz * kLen;
    const int l = tid & 63, wv = tid >> 6;
    const int wr = (wv >> 1) * (BM / 2), wc = (wv & 1) * (BN / 2);
    constexpr int MR = BM / 32, NR = BN / 32;
    const int fr = l & 15, q = l >> 4;

    constexpr int CA = (BM * 4) / 256;   // 16B chunks per thread, per A plane
    constexpr int CB = (BN * 4) / 256;

    u16x8 rAh[CA], rAl[CA], rBh[CB], rBl[CB];

    f32x4 acc[MR][NR];
#pragma unroll
    for (int m = 0; m < MR; ++m)
#pragma unroll
        for (int n = 0; n < NR; ++n) acc[m][n] = (f32x4){0.f, 0.f, 0.f, 0.f};

    // prologue: load tile 0
#pragma unroll
    for (int c = 0; c < CA; ++c) {
        int cc = c * 256 + tid, row = cc >> 2, qq = cc & 3;
        size_t off = (size_t)(bm + row) * K + kStart + qq * 8;
        rAh[c] = *(const u16x8*)(Agh + off);
        rAl[c] = *(const u16x8*)(Agl + off);
    }
#pragma unroll
    for (int c = 0; c < CB; ++c) {
        int cc = c * 256 + tid, row = cc >> 2, qq = cc & 3;
        size_t off = (size_t)(bn + row) * K + kStart + qq * 8;
        rBh[c] = *(const u16x8*)(Bgh + off);
        rBl[c] = *(const u16x8*)(Bgl + off);
    }

    for (int ks = 0; ks < kLen; ks += 32) {
        // write staged regs to LDS (waits vmcnt on the loads issued last iter)
#pragma unroll
        for (int c = 0; c < CA; ++c) {
            int cc = c * 256 + tid, row = cc >> 2, qq = cc & 3;
            int byte = swz_byte(row, qq);
            *(u16x8*)((char*)Ah + byte) = rAh[c];
            *(u16x8*)((char*)Al + byte) = rAl[c];
        }
#pragma unroll
        for (int c = 0; c < CB; ++c) {
            int cc = c * 256 + tid, row = cc >> 2, qq = cc & 3;
            int byte = swz_byte(row, qq);
            *(u16x8*)((char*)Bh + byte) = rBh[c];
            *(u16x8*)((char*)Bl + byte) = rBl[c];
        }
        // issue next tile's loads; they complete under the MFMA phase
        if (ks + 32 < kLen) {
            int k1 = kStart + ks + 32;
#pragma unroll
            for (int c = 0; c < CA; ++c) {
                int cc = c * 256 + tid, row = cc >> 2, qq = cc & 3;
                size_t off = (size_t)(bm + row) * K + k1 + qq * 8;
                rAh[c] = *(const u16x8*)(Agh + off);
                rAl[c] = *(const u16x8*)(Agl + off);
            }
#pragma unroll
            for (int c = 0; c < CB; ++c) {
                int cc = c * 256 + tid, row = cc >> 2, qq = cc & 3;
                size_t off = (size_t)(bn + row) * K + k1 + qq * 8;
                rBh[c] = *(const u16x8*)(Bgh + off);
                rBl[c] = *(const u16x8*)(Bgl + off);
            }
        }
        __syncthreads();

        bf16x8 ah[MR], av[MR], bh[NR], bv[NR];
#pragma unroll
        for (int m = 0; m < MR; ++m) {
            int row = wr + m * 16 + fr;
            ah[m] = rdfrag(Ah, row, q);
            av[m] = rdfrag(Al, row, q);
        }
#pragma unroll
        for (int n = 0; n < NR; ++n) {
            int row = wc + n * 16 + fr;
            bh[n] = rdfrag(Bh, row, q);
            bv[n] = rdfrag(Bl, row, q);
        }
#pragma unroll
        for (int m = 0; m < MR; ++m)
#pragma unroll
            for (int n = 0; n < NR; ++n) {
                acc[m][n] = __builtin_amdgcn_mfma_f32_16x16x32_bf16(av[m], bh[n], acc[m][n], 0, 0, 0);
                acc[m][n] = __builtin_amdgcn_mfma_f32_16x16x32_bf16(ah[m], bv[n], acc[m][n], 0, 0, 0);
                acc[m][n] = __builtin_amdgcn_mfma_f32_16x16x32_bf16(ah[m], bh[n], acc[m][n], 0, 0, 0);
            }
        __syncthreads();
    }

    float* Cz = C + (size_t)bz * M * N;
#pragma unroll
    for (int m = 0; m < MR; ++m)
#pragma unroll
        for (int n = 0; n < NR; ++n) {
            int row0 = bm + wr + m * 16 + q * 4;
            int col  = bn + wc + n * 16 + fr;
#pragma unroll
            for (int r = 0; r < 4; ++r)
                Cz[(size_t)(row0 + r) * N + col] = acc[m][n][r];
        }
}

// ---------------- xdbl split-K MFMA from planes
__global__ __launch_bounds__(256) void xdbl_mfma(const unsigned short* __restrict__ xch,
                                                 const unsigned short* __restrict__ xcl,
                                                 const unsigned short* __restrict__ Wxh,
                                                 const unsigned short* __restrict__ Wxl,
                                                 float* __restrict__ part) {
    __shared__ __align__(16) unsigned short Ah[128 * 32];
    __shared__ __align__(16) unsigned short Al[128 * 32];
    __shared__ __align__(16) unsigned short Bh[48 * 32];
    __shared__ __align__(16) unsigned short Bl[48 * 32];

    const int tid = threadIdx.x;
    const int bm = blockIdx.x * 128;
    const int kc = blockIdx.y;
    const int l = tid & 63, wv = tid >> 6;
    const int wr = wv * 32;
    const int fr = l & 15, q = l >> 4;

    f32x4 acc[2][3];
#pragma unroll
    for (int m = 0; m < 2; ++m)
#pragma unroll
        for (int n = 0; n < 3; ++n) acc[m][n] = (f32x4){0.f, 0.f, 0.f, 0.f};

    for (int ks = 0; ks < XKK; ks += 32) {
        int k0 = kc * XKK + ks;
        stage_pl<128>(xch + (size_t)bm * DI, xcl + (size_t)bm * DI, DI, k0, Ah, Al, tid);
        stage_pl<48>(Wxh, Wxl, DI, k0, Bh, Bl, tid);
        __syncthreads();

        bf16x8 ah[2], av[2], bh[3], bv[3];
#pragma unroll
        for (int m = 0; m < 2; ++m) {
            int row = wr + m * 16 + fr;
            ah[m] = rdfrag(Ah, row, q);
            av[m] = rdfrag(Al, row, q);
        }
#pragma unroll
        for (int n = 0; n < 3; ++n) {
            int row = n * 16 + fr;
            bh[n] = rdfrag(Bh, row, q);
            bv[n] = rdfrag(Bl, row, q);
        }
#pragma unroll
        for (int m = 0; m < 2; ++m)
#pragma unroll
            for (int n = 0; n < 3; ++n) {
                acc[m][n] = __builtin_amdgcn_mfma_f32_16x16x32_bf16(av[m], bh[n], acc[m][n], 0, 0, 0);
                acc[m][n] = __builtin_amdgcn_mfma_f32_16x16x32_bf16(ah[m], bv[n], acc[m][n], 0, 0, 0);
                acc[m][n] = __builtin_amdgcn_mfma_f32_16x16x32_bf16(ah[m], bh[n], acc[m][n], 0, 0, 0);
            }
        __syncthreads();
    }

#pragma unroll
    for (int m = 0; m < 2; ++m)
#pragma unroll
        for (int n = 0; n < 3; ++n) {
            int row0 = bm + wr + m * 16 + q * 4;
            int col  = n * 16 + fr;
#pragma unroll
            for (int r = 0; r < 4; ++r)
                part[(size_t)kc * (L * 48) + (size_t)(row0 + r) * 48 + col] = acc[m][n][r];
        }
}

__global__ __launch_bounds__(256) void xdbl_reduce(const float* __restrict__ part,
                                                   float* __restrict__ xdbl) {
    int i = blockIdx.x * 256 + threadIdx.x;
    float s = 0.f;
#pragma unroll
    for (int kc = 0; kc < XKC; ++kc) s += part[(size_t)kc * (L * 48) + i];
    xdbl[i] = s;
}

// ---------------- depthwise causal conv (k=4) + silu; writes fp32 xc + bf16 planes
__global__ __launch_bounds__(256) void conv_silu_kernel(const float* __restrict__ xz,
                                                        const float* __restrict__ cw,
                                                        const float* __restrict__ cb,
                                                        float* __restrict__ xc,
                                                        unsigned short* __restrict__ xch,
                                                        unsigned short* __restrict__ xcl) {
    int idx = blockIdx.x * 256 + threadIdx.x;   // l*(DI/4) + d4
    int l = idx >> 9;
    int d = (idx & 511) << 2;
    float4 s = *(const float4*)(cb + d);
    float4 w0 = *(const float4*)(cw + (d + 0) * 4);
    float4 w1 = *(const float4*)(cw + (d + 1) * 4);
    float4 w2 = *(const float4*)(cw + (d + 2) * 4);
    float4 w3 = *(const float4*)(cw + (d + 3) * 4);
#pragma unroll
    for (int k = 0; k < DCONV; ++k) {
        int t = l - (DCONV - 1) + k;
        if (t >= 0) {
            float4 xv = *(const float4*)(xz + (size_t)t * (2 * DI) + d);
            s.x += ((const float*)&w0)[k] * xv.x;
            s.y += ((const float*)&w1)[k] * xv.y;
            s.z += ((const float*)&w2)[k] * xv.z;
            s.w += ((const float*)&w3)[k] * xv.w;
        }
    }
    float4 o;
    o.x = s.x / (1.f + expf(-s.x));
    o.y = s.y / (1.f + expf(-s.y));
    o.z = s.z / (1.f + expf(-s.z));
    o.w = s.w / (1.f + expf(-s.w));
    *(float4*)(xc + (size_t)l * DI + d) = o;
    split4(o, xch, xcl, (size_t)idx);
}

// ---------------- delta[l,d] = softplus(xdbl[l,:16] @ W_dt[d,:] + b_dt[d])
__global__ __launch_bounds__(256) void delta_kernel(const float* __restrict__ xdbl,
                                                    const float* __restrict__ Wdt,
                                                    const float* __restrict__ bdt,
                                                    float* __restrict__ delta) {
    int idx = blockIdx.x * 256 + threadIdx.x;
    int l = idx >> 11;
    int d = idx & (DI - 1);
    float s = bdt[d];
    const float4* xr = (const float4*)(xdbl + l * 48);
    const float4* wr = (const float4*)(Wdt + d * RNK);
#pragma unroll
    for (int c = 0; c < 4; ++c) {
        float4 xv = xr[c], wv = wr[c];
        s += xv.x * wv.x + xv.y * wv.y + xv.z * wv.z + xv.w * wv.w;
    }
    delta[idx] = fmaxf(s, 0.f) + log1pf(expf(-fabsf(s)));   // jax softplus
}

// ---------------- scan phase A: register-resident n (no shuffles)
__global__ __launch_bounds__(256) void scan_a(const float* __restrict__ delta,
                                              const float* __restrict__ xc,
                                              const float* __restrict__ xdbl,
                                              const float* __restrict__ A_log,
                                              float* __restrict__ hloc,
                                              float* __restrict__ dsum) {
    __shared__ float sb[TCH][16];
    const int tid = threadIdx.x;
    const int c = blockIdx.x >> 3;                 // DI/256 = 8 blocks per chunk
    const int d = ((blockIdx.x & 7) << 8) + tid;
    const int t0 = c * TCH;
    for (int i = tid; i < TCH * 16; i += 256) {
        int tt = i >> 4, n = i & 15;
        sb[tt][n] = xdbl[(t0 + tt) * 48 + RNK + n];
    }
    __syncthreads();

    float Adn[16], h[16];
#pragma unroll
    for (int n = 0; n < 16; ++n) {
        Adn[n] = -expf(A_log[d * 16 + n]);
        h[n] = 0.f;
    }
    float ds = 0.f;
    for (int t = t0; t < t0 + TCH; ++t) {
        float dl = delta[(size_t)t * DI + d];
        float u  = xc[(size_t)t * DI + d];
        float du = dl * u;
        ds += dl;
        const float4* b4 = (const float4*)sb[t - t0];
#pragma unroll
        for (int j = 0; j < 4; ++j) {
            float4 b = b4[j];
            h[4*j+0] = __expf(Adn[4*j+0] * dl) * h[4*j+0] + du * b.x;
            h[4*j+1] = __expf(Adn[4*j+1] * dl) * h[4*j+1] + du * b.y;
            h[4*j+2] = __expf(Adn[4*j+2] * dl) * h[4*j+2] + du * b.z;
            h[4*j+3] = __expf(Adn[4*j+3] * dl) * h[4*j+3] + du * b.w;
        }
    }
    size_t base = ((size_t)c * DI + d) * 16;
#pragma unroll
    for (int j = 0; j < 4; ++j) {
        float4 o = {h[4*j+0], h[4*j+1], h[4*j+2], h[4*j+3]};
        *(float4*)(hloc + base + 4*j) = o;
    }
    dsum[c * DI + d] = ds;
}

// ---------------- scan phase B: inter-chunk combine; hinit written in place
__global__ __launch_bounds__(256) void scan_b(float* __restrict__ hloc,
                                              const float* __restrict__ dsum,
                                              const float* __restrict__ A_log) {
    int i = blockIdx.x * 256 + threadIdx.x;   // d*16+n  (== A_log flat index)
    float Adn = -expf(A_log[i]);
    float h = 0.f;
    for (int c = 0; c < CCH; ++c) {
        size_t off = (size_t)c * (DI * NST) + i;
        float hl = hloc[off];
        hloc[off] = h;                         // becomes hinit
        h = __expf(Adn * dsum[c * DI + (i >> 4)]) * h + hl;
    }
}

// ---------------- scan phase C: replay with correct init; in-register C-dot
__global__ __launch_bounds__(256) void scan_c(const float* __restrict__ delta,
                                              const float* __restrict__ xc,
                                              const float* __restrict__ xdbl,
                                              const float* __restrict__ A_log,
                                              const float* __restrict__ hinit,
                                              float* __restrict__ y /* stride 2*DI */) {
    __shared__ float sb[TCH][16];
    __shared__ float sc[TCH][16];
    const int tid = threadIdx.x;
    const int c = blockIdx.x >> 3;
    const int d = ((blockIdx.x & 7) << 8) + tid;
    const int t0 = c * TCH;
    for (int i = tid; i < TCH * 16; i += 256) {
        int tt = i >> 4, n = i & 15;
        sb[tt][n] = xdbl[(t0 + tt) * 48 + RNK + n];
        sc[tt][n] = xdbl[(t0 + tt) * 48 + RNK + NST + n];
    }
    __syncthreads();

    float Adn[16], h[16];
    size_t base = ((size_t)c * DI + d) * 16;
#pragma unroll
    for (int j = 0; j < 4; ++j) {
        float4 hv = *(const float4*)(hinit + base + 4*j);
        h[4*j+0] = hv.x; h[4*j+1] = hv.y; h[4*j+2] = hv.z; h[4*j+3] = hv.w;
    }
#pragma unroll
    for (int n = 0; n < 16; ++n) Adn[n] = -expf(A_log[d * 16 + n]);

    for (int t = t0; t < t0 + TCH; ++t) {
        float dl = delta[(size_t)t * DI + d];
        float u  = xc[(size_t)t * DI + d];
        float du = dl * u;
        const float4* b4 = (const float4*)sb[t - t0];
        const float4* c4 = (const float4*)sc[t - t0];
        float acc = 0.f;
#pragma unroll
        for (int j = 0; j < 4; ++j) {
            float4 b = b4[j];
            float4 ct = c4[j];
            h[4*j+0] = __expf(Adn[4*j+0] * dl) * h[4*j+0] + du * b.x;
            h[4*j+1] = __expf(Adn[4*j+1] * dl) * h[4*j+1] + du * b.y;
            h[4*j+2] = __expf(Adn[4*j+2] * dl) * h[4*j+2] + du * b.z;
            h[4*j+3] = __expf(Adn[4*j+3] * dl) * h[4*j+3] + du * b.w;
            acc += h[4*j+0] * ct.x + h[4*j+1] * ct.y + h[4*j+2] * ct.z + h[4*j+3] * ct.w;
        }
        y[(size_t)t * (2 * DI) + d] = acc;
    }
}

// ---------------- fused: gate -> g planes  AND  split W_out -> planes
#define GF4  (L * DI / 4)      // 1048576 / 4 ... = 1048576? (L*DI/4 = 1048576)
#define WOF4 (DM * DI / 4)     // 524288
__global__ __launch_bounds__(256) void gate_wout_kernel(const float* __restrict__ xz,
                                                        const float* __restrict__ xc,
                                                        const float* __restrict__ Dp,
                                                        const float* __restrict__ W_out,
                                                        unsigned short* __restrict__ gh,
                                                        unsigned short* __restrict__ gl,
                                                        unsigned short* __restrict__ Wouth,
                                                        unsigned short* __restrict__ Woutl) {
    int idx = blockIdx.x * 256 + threadIdx.x;
    if (idx < GF4) {
        int l = idx >> 9;
        int d = (idx & 511) << 2;
        float4 yv = *(const float4*)(xz + (size_t)l * (2 * DI) + d);
        float4 rv = *(const float4*)(xz + (size_t)l * (2 * DI) + DI + d);
        float4 xv = *(const float4*)(xc + (size_t)l * DI + d);
        float4 dv = *(const float4*)(Dp + d);
        float4 o;
        o.x = (yv.x + xv.x * dv.x) * (rv.x / (1.f + expf(-rv.x)));
        o.y = (yv.y + xv.y * dv.y) * (rv.y / (1.f + expf(-rv.y)));
        o.z = (yv.z + xv.z * dv.z) * (rv.z / (1.f + expf(-rv.z)));
        o.w = (yv.w + xv.w * dv.w) * (rv.w / (1.f + expf(-rv.w)));
        split4(o, gh, gl, (size_t)idx);
    } else {
        int j = idx - GF4;
        if (j < WOF4) split4(((const float4*)W_out)[j], Wouth, Woutl, j);
    }
}

// ---------------- out_proj split-K reduce
__global__ __launch_bounds__(256) void out_reduce(const float* __restrict__ part,
                                                  float* __restrict__ out) {
    int i = blockIdx.x * 256 + threadIdx.x;
    float4 a = ((const float4*)part)[i];
    float4 b = ((const float4*)(part + (size_t)L * DM))[i];
    float4 o = {a.x + b.x, a.y + b.y, a.z + b.z, a.w + b.w};
    ((float4*)out)[i] = o;
}

extern "C" void kernel_launch(void* const* d_in, const int* in_sizes, int n_in,
                              void* d_out, int out_size, void* d_ws, size_t ws_size,
                              hipStream_t stream) {
    const float* x      = (const float*)d_in[0];
    const float* W_in   = (const float*)d_in[1];
    const float* conv_w = (const float*)d_in[2];
    const float* conv_b = (const float*)d_in[3];
    const float* W_x    = (const float*)d_in[4];
    const float* W_dt   = (const float*)d_in[5];
    const float* b_dt   = (const float*)d_in[6];
    const float* A_log  = (const float*)d_in[7];
    const float* Dp     = (const float*)d_in[8];
    const float* W_out  = (const float*)d_in[9];
    float* out = (float*)d_out;

    float* ws = (float*)d_ws;
    // fp32 regions (total 19.1M floats = 76.5 MB — same as round 5)
    const size_t XZ_OFF    = 0;                                // xz (s1-s8); out partials (s9)
    const size_t XC_OFF    = XZ_OFF + (size_t)L * 2 * DI;      // Win planes (s0-s1); xc fp32 (s2-s8)
    const size_t DELTA_OFF = XC_OFF + (size_t)L * DI;          // x planes (s0-s1); xc planes (s2-s3); delta (s4-s7); g planes (s8-s9)
    const size_t XDBL_OFF  = DELTA_OFF + (size_t)L * DI;       // xdbl
    const size_t HLOC_OFF  = XDBL_OFF + 131072;                // xdbl part (s3); hloc/hinit (s5-s7); Wout planes (s8-s9)
    const size_t DSUM_OFF  = HLOC_OFF + (size_t)CCH * DI * NST; // Wx planes (s0-s3); dsum (s5-s6)

    float* xz    = ws + XZ_OFF;
    float* xc    = ws + XC_OFF;
    float* delta = ws + DELTA_OFF;
    float* xdbl  = ws + XDBL_OFF;
    float* hloc  = ws + HLOC_OFF;
    float* dsum  = ws + DSUM_OFF;
    float* part  = hloc;                 // xdbl partials (1.57M fl <= 2.1M)
    float* y     = xz;                   // scan output into xz[:, :DI]
    float* opart = xz;                   // out_proj split-K partials (4.19M <= 8.39M)

    // bf16 plane aliases
    unsigned short* xh    = (unsigned short*)(ws + DELTA_OFF);
    unsigned short* xl    = xh + (size_t)L * DM;
    unsigned short* Winh  = (unsigned short*)(ws + XC_OFF);
    unsigned short* Winl  = Winh + (size_t)2 * DI * DM;
    unsigned short* xch   = (unsigned short*)(ws + DELTA_OFF);
    unsigned short* xcl   = xch + (size_t)L * DI;
    unsigned short* Wxh   = (unsigned short*)(ws + DSUM_OFF);
    unsigned short* Wxl   = Wxh + (size_t)48 * DI;
    unsigned short* gh    = (unsigned short*)(ws + DELTA_OFF);
    unsigned short* gl    = gh + (size_t)L * DI;
    unsigned short* Wouth = (unsigned short*)(ws + HLOC_OFF);
    unsigned short* Woutl = Wouth + (size_t)DM * DI;

    // 0. fused pre-split of x, W_in, W_x
    split3_kernel<<<(XF4 + WINF4 + WXF4 + 255) / 256, 256, 0, stream>>>(
        x, W_in, W_x, xh, xl, Winh, Winl, Wxh, Wxl);

    // 1. in_proj: xz[L, 2*DI] = x @ W_in^T   (512 blocks, XCD-swizzled)
    gemm_pl<128, 128><<<dim3(L / 128, (2 * DI) / 128, 1), 256, 0, stream>>>(
        xh, xl, Winh, Winl, xz, L, 2 * DI, DM, DM);

    // 2. conv + silu -> xc fp32 + planes
    conv_silu_kernel<<<(L * DI / 4) / 256, 256, 0, stream>>>(xz, conv_w, conv_b, xc, xch, xcl);

    // 3. x_dbl: split-K MFMA + reduce
    xdbl_mfma<<<dim3(L / 128, XKC), 256, 0, stream>>>(xch, xcl, Wxh, Wxl, part);
    xdbl_reduce<<<(L * 48) / 256, 256, 0, stream>>>(part, xdbl);

    // 4. delta
    delta_kernel<<<(L * DI) / 256, 256, 0, stream>>>(xdbl, W_dt, b_dt, delta);

    // 5-7. selective scan (register-n formulation)
    scan_a<<<CCH * (DI / 256), 256, 0, stream>>>(delta, xc, xdbl, A_log, hloc, dsum);
    scan_b<<<(DI * NST) / 256, 256, 0, stream>>>(hloc, dsum, A_log);
    scan_c<<<CCH * (DI / 256), 256, 0, stream>>>(delta, xc, xdbl, A_log, hloc, y);

    // 8. fused gate (-> g planes in delta region) + W_out split (-> hloc region)
    gate_wout_kernel<<<(GF4 + WOF4 + 255) / 256, 256, 0, stream>>>(
        xz, xc, Dp, W_out, gh, gl, Wouth, Woutl);

    // 9. out_proj: full 128^2 tile, split-K x2 (16x8x2 = 256 blocks, swizzled)
    gemm_pl<128, 128><<<dim3(L / 128, DM / 128, 2), 256, 0, stream>>>(
        gh, gl, Wouth, Woutl, opart, L, DM, DI, DI / 2);
    out_reduce<<<(L * DM / 4) / 256, 256, 0, stream>>>(opart, out);
}